// Round 4
// baseline (74876.447 us; speedup 1.0000x reference)
//
#include <hip/hip_runtime.h>
#include <hip/hip_bf16.h>

typedef __bf16 bf16;
typedef __bf16 bf16x8 __attribute__((ext_vector_type(8)));
typedef float  f32x4  __attribute__((ext_vector_type(4)));

#define NT   600
#define NB   128
#define NS   512
#define NU   96
#define NK   10
#define NC   80
#define NOUT 121

// packed-weight element offsets in ws (bf16 elements), layout [slab][kb][lane][8]
#define W1X_J 0
#define W1W_J 16384
#define W1H_J 65536
#define W1X_K 327680
#define W1W_K 344064
#define W1H_K 393216
#define W2X_J 655360
#define W2W_J 671744
#define W2A_J 720896
#define W2H_J 983040
#define W2X_K 1245184
#define W2W_K 1261568
#define W2A_K 1310720
#define W2H_K 1572864
#define WWIN  1835008
#define WLIN  1851392

#define BIAS_BYTE_OFF 3833856         // 2048 floats: [b1j|b1k|b2j|b2k]
#define H_BYTE_OFF    3842048         // h1[2][128][512], h2..., h3... bf16
#define HBUF 65536                    // elements per parity buffer
#define FLAG_BYTE_OFF 4659200         // int isF32
#define BAR_BYTE_OFF  4659264         // int bar[640]: grp[8*64] | root@512 | epoch@576

// dual-dtype input load: isF32 is wave-uniform; if/else so the untaken
// (possibly OOB) load is never issued.
__device__ __forceinline__ float ldIn(const void* q, long i, int isF32) {
  if (isF32) return ((const float*)q)[i];
  return (float)((const bf16*)q)[i];
}

struct KParams {
  const void* x;       // [128][600][3]
  const void* c_vec;   // [128][96][80]
  const void* b_win;   // [30]
  const void* b_lin;   // [121]
  const bf16* W;       // packed weights base
  const float* bias;   // [4*512]
  bf16* h1; bf16* h2; bf16* h3;  // [2][128][512] each
  void* out;           // [128*600][121]
  const int* flag;
  int* bar;
};

// ---------------- two-level grid barrier (plain launch, device-scope) ----------------
__device__ __forceinline__ void grid_barrier(int* bar, int target) {
  __threadfence();                 // release: flush this block's writes device-wide
  __syncthreads();
  if (threadIdx.x == 0) {
    int* grpC  = bar + (blockIdx.x & 7) * 64;
    int* rootC = bar + 512;
    int* ep    = bar + 576;
    if (__hip_atomic_fetch_add(grpC, 1, __ATOMIC_RELAXED, __HIP_MEMORY_SCOPE_AGENT) == 31) {
      __hip_atomic_store(grpC, 0, __ATOMIC_RELAXED, __HIP_MEMORY_SCOPE_AGENT);
      if (__hip_atomic_fetch_add(rootC, 1, __ATOMIC_RELAXED, __HIP_MEMORY_SCOPE_AGENT) == 7) {
        __hip_atomic_store(rootC, 0, __ATOMIC_RELAXED, __HIP_MEMORY_SCOPE_AGENT);
        __hip_atomic_fetch_add(ep, 1, __ATOMIC_RELAXED, __HIP_MEMORY_SCOPE_AGENT);
      }
    }
    while (__hip_atomic_load(ep, __ATOMIC_RELAXED, __HIP_MEMORY_SCOPE_AGENT) < target) {
      __builtin_amdgcn_s_sleep(2);
    }
  }
  __syncthreads();
  __threadfence();                 // acquire: invalidate stale L1/L2 before reads
}

// ---------------- sniff: decide f32 vs bf16 input encoding ----------------
__global__ void sniff_kernel(const unsigned short* w, int* flag) {
  __shared__ int cnt;
  if (threadIdx.x == 0) cnt = 0;
  __syncthreads();
  int c = 0;
  for (int i = threadIdx.x; i < 8192; i += 256) {
    unsigned e = (w[2 * i] >> 7) & 0xFF;
    if (e == 0xFF || e < 96) c++;
  }
  atomicAdd(&cnt, c);
  __syncthreads();
  if (threadIdx.x == 0) *flag = (cnt > 512) ? 1 : 0;
}

// ---------------- prep: repack weights + zero state + zero barrier ----------------
__global__ void prep_kernel(const void* Wjx1, const void* Wjh1, const void* Wkx1, const void* Wkh1,
                            const void* Wjx2, const void* Wjh2, const void* Wkx2, const void* Wkh2,
                            const void* Wwin, const void* Wlin,
                            const void* bjx1, const void* bjh1, const void* bkx1, const void* bkh1,
                            const void* bjx2, const void* bjh2, const void* bkx2, const void* bkh2,
                            bf16* W, float* bias,
                            bf16* h1, bf16* h2, bf16* h3, int* bar,
                            const int* flag) {
  const int isF32 = *flag;
  const int r = blockIdx.y;
  const int e = blockIdx.x * 256 + threadIdx.x;
  if (r == 16) {                       // combined biases (f32)
    if (e < 512) {
      bias[e]        = ldIn(bjx1, e, isF32) + ldIn(bjh1, e, isF32);
      bias[512 + e]  = ldIn(bkx1, e, isF32) + ldIn(bkh1, e, isF32);
      bias[1024 + e] = ldIn(bjx2, e, isF32) + ldIn(bjh2, e, isF32);
      bias[1536 + e] = ldIn(bkx2, e, isF32) + ldIn(bkh2, e, isF32);
    }
    return;
  }
  if (r == 17) {                       // zero parity-1 state + barrier block
    if (e < HBUF) {
      h1[HBUF + e] = (bf16)0.f;
      h2[HBUF + e] = (bf16)0.f;
      h3[HBUF + e] = (bf16)0.f;
    }
    if (e < 640) bar[e] = 0;
    return;
  }
  const int   row0s[16]  = {0,3,0, 0,3,0, 0,515,3,0, 0,515,3,0, 0,0};
  const int   klens[16]  = {3,80,512, 3,80,512, 3,80,512,512, 3,80,512,512, 512,512};
  const int   kpads[16]  = {32,96,512, 32,96,512, 32,96,512,512, 32,96,512,512, 512,512};
  const int   cpads[16]  = {512,512,512, 512,512,512, 512,512,512,512, 512,512,512,512, 32,128};
  const int   nsrcs[16]  = {512,512,512, 512,512,512, 512,512,512,512, 512,512,512,512, 30,121};
  const long  offs[16]   = {W1X_J,W1W_J,W1H_J, W1X_K,W1W_K,W1H_K,
                            W2X_J,W2W_J,W2A_J,W2H_J, W2X_K,W2W_K,W2A_K,W2H_K, WWIN,WLIN};
  const void* srcs[16]   = {Wjx1,Wjx1,Wjh1, Wkx1,Wkx1,Wkh1,
                            Wjx2,Wjx2,Wjx2,Wjh2, Wkx2,Wkx2,Wkx2,Wkh2, Wwin,Wlin};
  const int Kpad = kpads[r], cp = cpads[r];
  const long tot = (long)Kpad * cp;
  if (e >= tot) return;
  const int j    = e & 7;
  const int lane = (e >> 3) & 63;
  const int rest = e >> 9;
  const int kbs  = Kpad >> 5;
  const int kb   = rest % kbs;
  const int slab = rest / kbs;
  const int col  = slab * 16 + (lane & 15);
  const int k    = kb * 32 + ((lane >> 4) << 3) + j;
  const int Klen = klens[r], row0 = row0s[r], N = nsrcs[r];
  bf16 v = (bf16)0.f;
  if (k < Klen && col < N) v = (bf16)ldIn(srcs[r], (long)(row0 + k) * N + col, isF32);
  W[offs[r] + e] = v;
}

// ---------------- shared MFMA helper ----------------
__device__ __forceinline__ void accum_term(f32x4& acc, int& cnt, int kh,
    const bf16* Arow, int astride, const bf16* B, int kbs,
    int lr, int ko, int lane) {
  for (int kb = 0; kb < kbs; ++kb) {
    if (((cnt++) & 1) != kh) continue;
    bf16x8 a = *(const bf16x8*)(Arow + (size_t)lr * astride + kb * 32 + ko);
    bf16x8 b = *(const bf16x8*)(B + ((size_t)kb * 64 + lane) * 8);
    acc = __builtin_amdgcn_mfma_f32_16x16x32_bf16(a, b, acc, 0, 0, 0);
  }
}

// ================= persistent scan kernel =================
__global__ __launch_bounds__(256) void scan_kernel(KParams p) {
  const int isF32 = *p.flag;
  const int tid  = threadIdx.x;
  const int wid  = tid >> 6;
  const int lane = tid & 63;
  const int wg   = blockIdx.x;       // 256 WGs, 1 per CU
  const int m    = wg >> 5;          // 8 m-tiles (16 batch rows)
  const int slab = wg & 31;          // 32 col-slabs (16 cols)
  const int m16  = m << 4;
  const int lr   = lane & 15;
  const int ko   = (lane >> 4) << 3;
  const int g    = wid >> 1;         // gate (0=j,1=k)
  const int kh   = wid & 1;          // K-half

  __shared__ alignas(16) bf16 xtL[16][32];
  __shared__ alignas(16) bf16 xt2L[16][32];
  __shared__ alignas(16) bf16 wL[16][96];
  __shared__ float kgL[16][32];
  __shared__ float kapL[16][NK];
  __shared__ float alphaL[16][NK];
  __shared__ float betaL[16][NK];
  __shared__ float wloL[16][16];
  __shared__ float whiL[16][16];
  __shared__ int   winL[16][2];
  __shared__ float phiL[16][NU];
  __shared__ f32x4 accA[4][64];
  __shared__ f32x4 accB[4][64];

  // init LDS-resident state (h parity-1 zeroed by prep kernel)
  for (int i = tid; i < 16 * 32; i += 256) { (&xtL[0][0])[i] = (bf16)0.f; (&xt2L[0][0])[i] = (bf16)0.f; }
  for (int i = tid; i < 16 * 96; i += 256) (&wL[0][0])[i] = (bf16)0.f;
  for (int i = tid; i < 16 * NK; i += 256) (&kapL[0][0])[i] = 0.f;
  __syncthreads();

  int bt = 0;
  for (int t = -1; t < NT; ++t) {
    const int par_t = t & 1;        // (-1)&1 == 1
    const int par_p = (t + 1) & 1;
    const bf16* h1t = p.h1 + (size_t)par_t * HBUF;

    if (t >= 0) {
      // ======== Stage P: attention(t) + ff2(t) + out-head(t-1) ========
      if (tid < 48) {
        int row = tid / 3, d = tid - row * 3;
        xtL[row][d] = (bf16)ldIn(p.x, ((long)(m16 + row) * NT + t) * 3 + d, isF32);
      }
      {  // kg = h1(t) @ W_win via MFMA
        int n2 = wid & 1, kh2 = wid >> 1;
        f32x4 acc = {0.f, 0.f, 0.f, 0.f};
        const bf16* A = h1t + (size_t)m16 * NS;
        const bf16* B = p.W + WWIN + (size_t)n2 * (16 * NS);
        for (int kb = 0; kb < 16; ++kb) {
          if ((kb & 1) != kh2) continue;
          bf16x8 a = *(const bf16x8*)(A + (size_t)lr * NS + kb * 32 + ko);
          bf16x8 b = *(const bf16x8*)(B + ((size_t)kb * 64 + lane) * 8);
          acc = __builtin_amdgcn_mfma_f32_16x16x32_bf16(a, b, acc, 0, 0, 0);
        }
        accA[wid][lane] = acc;
      }
      __syncthreads();
      if (tid < 128) {  // kg epilogue
        int ls = tid & 63, n2s = tid >> 6;
        int o = n2s * 16 + (ls & 15);
        if (o < 30) {
          int rowb = (ls >> 4) << 2;
          for (int r = 0; r < 4; ++r)
            kgL[rowb + r][o] = accA[n2s][ls][r] + accA[n2s + 2][ls][r] + ldIn(p.b_win, o, isF32);
        }
      }
      __syncthreads();
      {  // attention scalars (kap kept in LDS across steps; same thread owns same slot)
        int arow = tid >> 4, aj = tid & 15;
        if (aj < NK) {
          float ah = kgL[arow][aj];
          float be = expf(kgL[arow][NK + aj]);
          float dk = expf(kgL[arow][2 * NK + aj]);
          float al = expf(ah);
          float kap = kapL[arow][aj] + dk;
          kapL[arow][aj] = kap;
          alphaL[arow][aj] = al;
          betaL[arow][aj] = be;
          float arg = (ah + 18.42f) / be;
          float lo, hi;
          if (arg > 0.f) { float R = sqrtf(arg); lo = kap - R; hi = kap + R; }
          else           { lo = 1e30f; hi = -1e30f; }
          wloL[arow][aj] = lo; whiL[arow][aj] = hi;
        } else { wloL[arow][aj] = 1e30f; whiL[arow][aj] = -1e30f; }
        __syncthreads();
        if (aj == 0) {
          float lo = 1e30f, hi = -1e30f;
          for (int k2 = 0; k2 < NK; ++k2) { lo = fminf(lo, wloL[arow][k2]); hi = fmaxf(hi, whiL[arow][k2]); }
          int ulo = (lo <= 0.f) ? 0 : ((lo > 95.f) ? 96 : (int)floorf(lo));
          int uhi = (hi >= 95.f) ? 95 : ((hi < 0.f) ? -1 : (int)ceilf(hi));
          winL[arow][0] = ulo; winL[arow][1] = uhi;
        }
        __syncthreads();
        const int ulo = winL[arow][0], uhi = winL[arow][1];
        for (int u = ulo + aj; u <= uhi; u += 16) {
          float s = 0.f, uf = (float)u;
          for (int k2 = 0; k2 < NK; ++k2) {
            float d = kapL[arow][k2] - uf;
            s += alphaL[arow][k2] * __expf(-betaL[arow][k2] * d * d);
          }
          phiL[arow][u] = s;
        }
        __syncthreads();
        {  // w = phi @ c_vec[b]
          const long cv0 = (long)(m16 + arow) * NU * NC;
          for (int c = aj; c < NC; c += 16) {
            float acc = 0.f;
            for (int u = ulo; u <= uhi; ++u)
              acc += phiL[arow][u] * ldIn(p.c_vec, cv0 + (long)u * NC + c, isF32);
            wL[arow][c] = (bf16)acc;
          }
        }
      }
      __syncthreads();
      {  // ff2 MFMAs: in2 = [xt, h1(t), w], recur h2(t-1)
        f32x4 acc = {0.f, 0.f, 0.f, 0.f};
        int cnt = 0;
        const size_t oX = g ? W2X_K : W2X_J, oA = g ? W2A_K : W2A_J;
        const size_t oW = g ? W2W_K : W2W_J, oH = g ? W2H_K : W2H_J;
        accum_term(acc, cnt, kh, &xtL[0][0], 32, p.W + oX + (size_t)slab * NS,        1,  lr, ko, lane);
        accum_term(acc, cnt, kh, h1t + (size_t)m16 * NS, NS, p.W + oA + (size_t)slab * (16 * NS), 16, lr, ko, lane);
        accum_term(acc, cnt, kh, &wL[0][0], 96, p.W + oW + (size_t)slab * (3 * NS),   3,  lr, ko, lane);
        accum_term(acc, cnt, kh, p.h2 + (size_t)par_p * HBUF + (size_t)m16 * NS, NS,
                   p.W + oH + (size_t)slab * (16 * NS), 16, lr, ko, lane);
        accA[wid][lane] = acc;
      }
      if (slab < 8 && t >= 1) {  // out-head MFMAs for rows (t-1)
        f32x4 acc = {0.f, 0.f, 0.f, 0.f};
        const bf16* A = p.h3 + (size_t)par_p * HBUF + (size_t)m16 * NS;
        const bf16* B = p.W + WLIN + (size_t)slab * (16 * NS);
        for (int kb = 0; kb < 16; ++kb) {
          if ((kb & 3) != wid) continue;
          bf16x8 a = *(const bf16x8*)(A + (size_t)lr * NS + kb * 32 + ko);
          bf16x8 b = *(const bf16x8*)(B + ((size_t)kb * 64 + lane) * 8);
          acc = __builtin_amdgcn_mfma_f32_16x16x32_bf16(a, b, acc, 0, 0, 0);
        }
        accB[wid][lane] = acc;
      }
      __syncthreads();
      {  // ff2 epilogue -> h2(t)
        int ls = tid & 63, r = tid >> 6;
        int s = (slab << 4) + (ls & 15);
        int b = m16 + ((ls >> 4) << 2) + r;
        float jp = accA[0][ls][r] + accA[1][ls][r] + p.bias[1024 + s];
        float kp = accA[2][ls][r] + accA[3][ls][r] + p.bias[1536 + s];
        float ho = (float)p.h2[(size_t)par_p * HBUF + (size_t)b * NS + s];
        float jj = 1.f / (1.f + __expf(-jp));
        float kk = 1.f / (1.f + __expf(-kp));
        p.h2[(size_t)par_t * HBUF + (size_t)b * NS + s] = (bf16)(jj * (1.f - ho) + (1.f - kk) * ho);
      }
      if (slab < 8 && t >= 1 && tid < 64) {  // out-head epilogue
        int o = (slab << 4) + (tid & 15);
        if (o < NOUT) {
          float bl = ldIn(p.b_lin, o, isF32);
          int rb = (tid >> 4) << 2;
          for (int r = 0; r < 4; ++r) {
            float v = accB[0][tid][r] + accB[1][tid][r] + accB[2][tid][r] + accB[3][tid][r] + bl;
            long oi = ((long)(m16 + rb + r) * NT + (t - 1)) * NOUT + o;
            if (isF32) ((float*)p.out)[oi] = v; else ((bf16*)p.out)[oi] = (bf16)v;
          }
        }
      }
      grid_barrier(p.bar, ++bt);
    }

    // ======== Stage Q: ff3(t) + ff1(t+1) ========
    if (t < NT - 1 && tid < 48) {
      int row = tid / 3, d = tid - row * 3;
      xt2L[row][d] = (bf16)ldIn(p.x, ((long)(m16 + row) * NT + (t + 1)) * 3 + d, isF32);
    }
    __syncthreads();
    f32x4 acc3 = {0.f, 0.f, 0.f, 0.f};
    f32x4 acc1 = {0.f, 0.f, 0.f, 0.f};
    if (t >= 0) {  // ff3: in3 = [xt, h2(t), w], recur h3(t-1)  (reuses rnn2 weights)
      int cnt = 0;
      const size_t oX = g ? W2X_K : W2X_J, oA = g ? W2A_K : W2A_J;
      const size_t oW = g ? W2W_K : W2W_J, oH = g ? W2H_K : W2H_J;
      accum_term(acc3, cnt, kh, &xtL[0][0], 32, p.W + oX + (size_t)slab * NS,        1,  lr, ko, lane);
      accum_term(acc3, cnt, kh, p.h2 + (size_t)par_t * HBUF + (size_t)m16 * NS, NS,
                 p.W + oA + (size_t)slab * (16 * NS), 16, lr, ko, lane);
      accum_term(acc3, cnt, kh, &wL[0][0], 96, p.W + oW + (size_t)slab * (3 * NS),   3,  lr, ko, lane);
      accum_term(acc3, cnt, kh, p.h3 + (size_t)par_p * HBUF + (size_t)m16 * NS, NS,
                 p.W + oH + (size_t)slab * (16 * NS), 16, lr, ko, lane);
    }
    if (t < NT - 1) {  // ff1(t+1): in1 = [xt(t+1), w(t)], recur h1(t)
      int cnt = 0;
      const size_t oX = g ? W1X_K : W1X_J, oW = g ? W1W_K : W1W_J, oH = g ? W1H_K : W1H_J;
      const bf16* h1t2 = p.h1 + (size_t)par_t * HBUF;
      accum_term(acc1, cnt, kh, &xt2L[0][0], 32, p.W + oX + (size_t)slab * NS,       1,  lr, ko, lane);
      accum_term(acc1, cnt, kh, &wL[0][0], 96, p.W + oW + (size_t)slab * (3 * NS),   3,  lr, ko, lane);
      accum_term(acc1, cnt, kh, h1t2 + (size_t)m16 * NS, NS, p.W + oH + (size_t)slab * (16 * NS), 16, lr, ko, lane);
    }
    accA[wid][lane] = acc3;
    accB[wid][lane] = acc1;
    __syncthreads();
    {
      int ls = tid & 63, r = tid >> 6;
      int s = (slab << 4) + (ls & 15);
      int b = m16 + ((ls >> 4) << 2) + r;
      if (t >= 0) {  // h3(t)
        float jp = accA[0][ls][r] + accA[1][ls][r] + p.bias[1024 + s];
        float kp = accA[2][ls][r] + accA[3][ls][r] + p.bias[1536 + s];
        float ho = (float)p.h3[(size_t)par_p * HBUF + (size_t)b * NS + s];
        float jj = 1.f / (1.f + __expf(-jp));
        float kk = 1.f / (1.f + __expf(-kp));
        p.h3[(size_t)par_t * HBUF + (size_t)b * NS + s] = (bf16)(jj * (1.f - ho) + (1.f - kk) * ho);
      }
      if (t < NT - 1) {  // h1(t+1)
        float jp = accB[0][ls][r] + accB[1][ls][r] + p.bias[0 + s];
        float kp = accB[2][ls][r] + accB[3][ls][r] + p.bias[512 + s];
        float ho = (float)p.h1[(size_t)par_t * HBUF + (size_t)b * NS + s];
        float jj = 1.f / (1.f + __expf(-jp));
        float kk = 1.f / (1.f + __expf(-kp));
        p.h1[(size_t)par_p * HBUF + (size_t)b * NS + s] = (bf16)(jj * (1.f - ho) + (1.f - kk) * ho);
      }
    }
    grid_barrier(p.bar, ++bt);
  }

  // final out-head row t = 599 (h3(599) is in parity 1)
  if (slab < 8) {
    f32x4 acc = {0.f, 0.f, 0.f, 0.f};
    const bf16* A = p.h3 + (size_t)HBUF + (size_t)m16 * NS;
    const bf16* B = p.W + WLIN + (size_t)slab * (16 * NS);
    for (int kb = 0; kb < 16; ++kb) {
      if ((kb & 3) != wid) continue;
      bf16x8 a = *(const bf16x8*)(A + (size_t)lr * NS + kb * 32 + ko);
      bf16x8 b = *(const bf16x8*)(B + ((size_t)kb * 64 + lane) * 8);
      acc = __builtin_amdgcn_mfma_f32_16x16x32_bf16(a, b, acc, 0, 0, 0);
    }
    accB[wid][lane] = acc;
    __syncthreads();
    if (tid < 64) {
      int o = (slab << 4) + (tid & 15);
      if (o < NOUT) {
        float bl = ldIn(p.b_lin, o, isF32);
        int rb = (tid >> 4) << 2;
        for (int r = 0; r < 4; ++r) {
          float v = accB[0][tid][r] + accB[1][tid][r] + accB[2][tid][r] + accB[3][tid][r] + bl;
          long oi = ((long)(m16 + rb + r) * NT + (NT - 1)) * NOUT + o;
          if (isF32) ((float*)p.out)[oi] = v; else ((bf16*)p.out)[oi] = (bf16)v;
        }
      }
    }
  }
}

extern "C" void kernel_launch(void* const* d_in, const int* in_sizes, int n_in,
                              void* d_out, int out_size, void* d_ws, size_t ws_size,
                              hipStream_t stream) {
  (void)in_sizes; (void)n_in; (void)out_size; (void)ws_size;

  bf16*  wsW  = (bf16*)d_ws;
  float* bias = (float*)((char*)d_ws + BIAS_BYTE_OFF);
  bf16*  h1   = (bf16*)((char*)d_ws + H_BYTE_OFF);
  bf16*  h2   = h1 + 2 * HBUF;
  bf16*  h3   = h2 + 2 * HBUF;
  int*   flag = (int*)((char*)d_ws + FLAG_BYTE_OFF);
  int*   bar  = (int*)((char*)d_ws + BAR_BYTE_OFF);

  sniff_kernel<<<1, 256, 0, stream>>>((const unsigned short*)d_in[4], flag);

  prep_kernel<<<dim3(1024, 18), 256, 0, stream>>>(
      d_in[2], d_in[4], d_in[6], d_in[8], d_in[10], d_in[12], d_in[14], d_in[16],
      d_in[18], d_in[20],
      d_in[3], d_in[5], d_in[7], d_in[9], d_in[11], d_in[13], d_in[15], d_in[17],
      wsW, bias, h1, h2, h3, bar, flag);

  KParams kp;
  kp.x = d_in[0]; kp.c_vec = d_in[1]; kp.b_win = d_in[19]; kp.b_lin = d_in[21];
  kp.W = wsW; kp.bias = bias;
  kp.h1 = h1; kp.h2 = h2; kp.h3 = h3;
  kp.out = d_out;
  kp.flag = flag;
  kp.bar = bar;

  scan_kernel<<<256, 256, 0, stream>>>(kp);
}

// Round 5
// 31750.476 us; speedup vs baseline: 2.3583x; 2.3583x over previous
//
#include <hip/hip_runtime.h>
#include <hip/hip_bf16.h>

typedef __bf16 bf16;
typedef __bf16 bf16x8 __attribute__((ext_vector_type(8)));
typedef float  f32x4  __attribute__((ext_vector_type(4)));

#define NT   600
#define NB   128
#define NS   512
#define NU   96
#define NK   10
#define NC   80
#define NOUT 121

// packed-weight element offsets in ws (bf16 elements), layout [slab][kb][lane][8]
#define W1X_J 0
#define W1W_J 16384
#define W1H_J 65536
#define W1X_K 327680
#define W1W_K 344064
#define W1H_K 393216
#define W2X_J 655360
#define W2W_J 671744
#define W2A_J 720896
#define W2H_J 983040
#define W2X_K 1245184
#define W2W_K 1261568
#define W2A_K 1310720
#define W2H_K 1572864
#define WWIN  1835008
#define WLIN  1851392

#define BIAS_BYTE_OFF 3833856         // 2048 floats: [b1j|b1k|b2j|b2k]
#define H_BYTE_OFF    3842048         // h1[2][128][512], h2..., h3... bf16
#define HBUF 65536                    // bf16 elements per parity buffer
#define HBUFD 32768                   // dwords per parity buffer
#define FLAG_BYTE_OFF 4659200         // int isF32
#define BAR_BYTE_OFF  4659264         // int bar[1024]: per group g: cnt@g*64, epoch@g*64+32

#define HSTRIDE 520                   // LDS h-tile row stride in bf16 (16B aligned, 2-way banks)

__device__ __forceinline__ float ldIn(const void* q, long i, int isF32) {
  if (isF32) return ((const float*)q)[i];
  return (float)((const bf16*)q)[i];
}

struct KParams {
  const void* x;       // [128][600][3]
  const void* c_vec;   // [128][96][80]
  const void* b_win;   // [30]
  const void* b_lin;   // [121]
  const bf16* W;       // packed weights base
  const float* bias;   // [4*512]
  bf16* h1; bf16* h2; bf16* h3;  // [2][128][512] each
  void* out;           // [128*600][121]
  const int* flag;
  int* bar;
};

// ---- per-m-group barrier: 32 arrivals, monotonic counter (no reset race), no cache fences ----
__device__ __forceinline__ void group_barrier(int* bar, int grp, int target) {
  __syncthreads();   // compiler drains each wave's vmem (incl. agent h-stores) before s_barrier
  if (threadIdx.x == 0) {
    int* cnt = bar + grp * 64;
    int* ep  = bar + grp * 64 + 32;
    int old = __hip_atomic_fetch_add(cnt, 1, __ATOMIC_RELAXED, __HIP_MEMORY_SCOPE_AGENT);
    if ((old & 31) == 31)
      __hip_atomic_fetch_add(ep, 1, __ATOMIC_RELAXED, __HIP_MEMORY_SCOPE_AGENT);
    while (__hip_atomic_load(ep, __ATOMIC_RELAXED, __HIP_MEMORY_SCOPE_AGENT) < target)
      __builtin_amdgcn_s_sleep(1);
  }
  __syncthreads();
  __atomic_signal_fence(__ATOMIC_ACQ_REL);  // compiler-only: no hoisting loads above the spin
}

// stage one 16x512 bf16 h-tile (4096 dwords) global->LDS via agent-coherent dword loads
__device__ __forceinline__ void stage_tile(const unsigned* gp, unsigned* ldsD, int tid) {
#pragma unroll
  for (int i = 0; i < 16; ++i)
    ldsD[i * 260 + tid] =
        __hip_atomic_load(gp + i * 256 + tid, __ATOMIC_RELAXED, __HIP_MEMORY_SCOPE_AGENT);
}

// assemble a bf16x8 A-fragment from agent-coherent dword loads (h3 paths)
__device__ __forceinline__ bf16x8 ldH8(const unsigned* gp, int row, int col) {
  union { unsigned u[4]; bf16x8 v; } x;
  const unsigned* q = gp + row * 256 + (col >> 1);
#pragma unroll
  for (int i = 0; i < 4; ++i)
    x.u[i] = __hip_atomic_load(q + i, __ATOMIC_RELAXED, __HIP_MEMORY_SCOPE_AGENT);
  return x.v;
}

__device__ __forceinline__ bf16 us2bf(unsigned short u) {
  union { unsigned short u; bf16 b; } c; c.u = u; return c.b;
}

// ---------------- sniff: decide f32 vs bf16 input encoding ----------------
__global__ void sniff_kernel(const unsigned short* w, int* flag) {
  __shared__ int cnt;
  if (threadIdx.x == 0) cnt = 0;
  __syncthreads();
  int c = 0;
  for (int i = threadIdx.x; i < 8192; i += 256) {
    unsigned e = (w[2 * i] >> 7) & 0xFF;
    if (e == 0xFF || e < 96) c++;
  }
  atomicAdd(&cnt, c);
  __syncthreads();
  if (threadIdx.x == 0) *flag = (cnt > 512) ? 1 : 0;
}

// ---------------- prep: repack weights + zero state + zero barriers ----------------
__global__ void prep_kernel(const void* Wjx1, const void* Wjh1, const void* Wkx1, const void* Wkh1,
                            const void* Wjx2, const void* Wjh2, const void* Wkx2, const void* Wkh2,
                            const void* Wwin, const void* Wlin,
                            const void* bjx1, const void* bjh1, const void* bkx1, const void* bkh1,
                            const void* bjx2, const void* bjh2, const void* bkx2, const void* bkh2,
                            bf16* W, float* bias,
                            bf16* h1, bf16* h2, bf16* h3, int* bar,
                            const int* flag) {
  const int isF32 = *flag;
  const int r = blockIdx.y;
  const int e = blockIdx.x * 256 + threadIdx.x;
  if (r == 16) {
    if (e < 512) {
      bias[e]        = ldIn(bjx1, e, isF32) + ldIn(bjh1, e, isF32);
      bias[512 + e]  = ldIn(bkx1, e, isF32) + ldIn(bkh1, e, isF32);
      bias[1024 + e] = ldIn(bjx2, e, isF32) + ldIn(bjh2, e, isF32);
      bias[1536 + e] = ldIn(bkx2, e, isF32) + ldIn(bkh2, e, isF32);
    }
    return;
  }
  if (r == 17) {
    if (e < HBUF) {
      h1[HBUF + e] = (bf16)0.f;
      h2[HBUF + e] = (bf16)0.f;
      h3[HBUF + e] = (bf16)0.f;
    }
    if (e < 1024) bar[e] = 0;
    return;
  }
  const int   row0s[16]  = {0,3,0, 0,3,0, 0,515,3,0, 0,515,3,0, 0,0};
  const int   klens[16]  = {3,80,512, 3,80,512, 3,80,512,512, 3,80,512,512, 512,512};
  const int   kpads[16]  = {32,96,512, 32,96,512, 32,96,512,512, 32,96,512,512, 512,512};
  const int   cpads[16]  = {512,512,512, 512,512,512, 512,512,512,512, 512,512,512,512, 32,128};
  const int   nsrcs[16]  = {512,512,512, 512,512,512, 512,512,512,512, 512,512,512,512, 30,121};
  const long  offs[16]   = {W1X_J,W1W_J,W1H_J, W1X_K,W1W_K,W1H_K,
                            W2X_J,W2W_J,W2A_J,W2H_J, W2X_K,W2W_K,W2A_K,W2H_K, WWIN,WLIN};
  const void* srcs[16]   = {Wjx1,Wjx1,Wjh1, Wkx1,Wkx1,Wkh1,
                            Wjx2,Wjx2,Wjx2,Wjh2, Wkx2,Wkx2,Wkx2,Wkh2, Wwin,Wlin};
  const int Kpad = kpads[r], cp = cpads[r];
  const long tot = (long)Kpad * cp;
  if (e >= tot) return;
  const int j    = e & 7;
  const int lane = (e >> 3) & 63;
  const int rest = e >> 9;
  const int kbs  = Kpad >> 5;
  const int kb   = rest % kbs;
  const int slab = rest / kbs;
  const int col  = slab * 16 + (lane & 15);
  const int k    = kb * 32 + ((lane >> 4) << 3) + j;
  const int Klen = klens[r], row0 = row0s[r], N = nsrcs[r];
  bf16 v = (bf16)0.f;
  if (k < Klen && col < N) v = (bf16)ldIn(srcs[r], (long)(row0 + k) * N + col, isF32);
  W[offs[r] + e] = v;
}

// ---------------- shared MFMA helper ----------------
__device__ __forceinline__ void accum_term(f32x4& acc, int& cnt, int kh,
    const bf16* Arow, int astride, const bf16* B, int kbs,
    int lr, int ko, int lane) {
  for (int kb = 0; kb < kbs; ++kb) {
    if (((cnt++) & 1) != kh) continue;
    bf16x8 a = *(const bf16x8*)(Arow + (size_t)lr * astride + kb * 32 + ko);
    bf16x8 b = *(const bf16x8*)(B + ((size_t)kb * 64 + lane) * 8);
    acc = __builtin_amdgcn_mfma_f32_16x16x32_bf16(a, b, acc, 0, 0, 0);
  }
}

// ================= persistent scan kernel =================
__global__ __launch_bounds__(256) void scan_kernel(KParams p) {
  const int isF32 = *p.flag;
  const int tid  = threadIdx.x;
  const int wid  = tid >> 6;
  const int lane = tid & 63;
  const int wg   = blockIdx.x;       // 256 WGs, 1 per CU
  const int m    = wg >> 5;          // 8 m-groups (16 batch rows each)
  const int slab = wg & 31;          // 32 col-slabs (16 cols each)
  const int m16  = m << 4;
  const int lr   = lane & 15;
  const int ko   = (lane >> 4) << 3;
  const int g    = wid >> 1;         // gate (0=j,1=k)
  const int kh   = wid & 1;          // K-half

  const unsigned* hg1 = (const unsigned*)p.h1;
  const unsigned* hg2c = (const unsigned*)p.h2;
  const unsigned* hg3 = (const unsigned*)p.h3;
  unsigned* hg1w = (unsigned*)p.h1;
  unsigned* hg2w = (unsigned*)p.h2;
  unsigned* hg3w = (unsigned*)p.h3;

  __shared__ alignas(16) bf16 h1L[16 * HSTRIDE];
  __shared__ alignas(16) bf16 h2L[16 * HSTRIDE];
  __shared__ alignas(16) bf16 xtL[16][32];
  __shared__ alignas(16) bf16 xt2L[16][32];
  __shared__ alignas(16) bf16 wL[16][96];
  __shared__ float kgL[16][32];
  __shared__ float kapL[16][NK];
  __shared__ float alphaL[16][NK];
  __shared__ float betaL[16][NK];
  __shared__ float wloL[16][16];
  __shared__ float whiL[16][16];
  __shared__ int   winL[16][2];
  __shared__ float phiL[16][NU];
  __shared__ f32x4 accA[4][64];
  __shared__ f32x4 accB[4][64];
  __shared__ bf16  hOutA[16][16];
  __shared__ bf16  hOutB[16][16];

  for (int i = tid; i < 16 * 32; i += 256) { (&xtL[0][0])[i] = (bf16)0.f; (&xt2L[0][0])[i] = (bf16)0.f; }
  for (int i = tid; i < 16 * 96; i += 256) (&wL[0][0])[i] = (bf16)0.f;
  for (int i = tid; i < 16 * NK; i += 256) (&kapL[0][0])[i] = 0.f;
  __syncthreads();

  int bt = 0;
  for (int t = -1; t < NT; ++t) {
    const int par_t = t & 1;        // (-1)&1 == 1
    const int par_p = (t + 1) & 1;

    if (t >= 0) {
      // ======== Stage P: attention(t) + ff2(t) + out-head(t-1) ========
      stage_tile(hg1 + par_t * HBUFD + (m16 << 8), (unsigned*)h1L, tid);
      stage_tile(hg2c + par_p * HBUFD + (m16 << 8), (unsigned*)h2L, tid);
      if (tid < 48) {
        int row = tid / 3, d = tid - row * 3;
        xtL[row][d] = (bf16)ldIn(p.x, ((long)(m16 + row) * NT + t) * 3 + d, isF32);
      }
      __syncthreads();
      {  // kg = h1(t) @ W_win via MFMA
        int n2 = wid & 1, kh2 = wid >> 1;
        f32x4 acc = {0.f, 0.f, 0.f, 0.f};
        const bf16* B = p.W + WWIN + (size_t)n2 * (16 * NS);
        for (int kb = 0; kb < 16; ++kb) {
          if ((kb & 1) != kh2) continue;
          bf16x8 a = *(const bf16x8*)(h1L + (size_t)lr * HSTRIDE + kb * 32 + ko);
          bf16x8 b = *(const bf16x8*)(B + ((size_t)kb * 64 + lane) * 8);
          acc = __builtin_amdgcn_mfma_f32_16x16x32_bf16(a, b, acc, 0, 0, 0);
        }
        accA[wid][lane] = acc;
      }
      __syncthreads();
      if (tid < 128) {  // kg epilogue
        int ls = tid & 63, n2s = tid >> 6;
        int o = n2s * 16 + (ls & 15);
        if (o < 30) {
          int rowb = (ls >> 4) << 2;
          for (int r = 0; r < 4; ++r)
            kgL[rowb + r][o] = accA[n2s][ls][r] + accA[n2s + 2][ls][r] + ldIn(p.b_win, o, isF32);
        }
      }
      __syncthreads();
      {  // attention scalars (kap in LDS across steps; same thread owns same slot)
        int arow = tid >> 4, aj = tid & 15;
        if (aj < NK) {
          float ah = kgL[arow][aj];
          float be = expf(kgL[arow][NK + aj]);
          float dk = expf(kgL[arow][2 * NK + aj]);
          float al = expf(ah);
          float kap = kapL[arow][aj] + dk;
          kapL[arow][aj] = kap;
          alphaL[arow][aj] = al;
          betaL[arow][aj] = be;
          float arg = (ah + 18.42f) / be;
          float lo, hi;
          if (arg > 0.f) { float R = sqrtf(arg); lo = kap - R; hi = kap + R; }
          else           { lo = 1e30f; hi = -1e30f; }
          wloL[arow][aj] = lo; whiL[arow][aj] = hi;
        } else { wloL[arow][aj] = 1e30f; whiL[arow][aj] = -1e30f; }
        __syncthreads();
        if (aj == 0) {
          float lo = 1e30f, hi = -1e30f;
          for (int k2 = 0; k2 < NK; ++k2) { lo = fminf(lo, wloL[arow][k2]); hi = fmaxf(hi, whiL[arow][k2]); }
          int ulo = (lo <= 0.f) ? 0 : ((lo > 95.f) ? 96 : (int)floorf(lo));
          int uhi = (hi >= 95.f) ? 95 : ((hi < 0.f) ? -1 : (int)ceilf(hi));
          winL[arow][0] = ulo; winL[arow][1] = uhi;
        }
        __syncthreads();
        const int ulo = winL[arow][0], uhi = winL[arow][1];
        for (int u = ulo + aj; u <= uhi; u += 16) {
          float s = 0.f, uf = (float)u;
          for (int k2 = 0; k2 < NK; ++k2) {
            float d = kapL[arow][k2] - uf;
            s += alphaL[arow][k2] * __expf(-betaL[arow][k2] * d * d);
          }
          phiL[arow][u] = s;
        }
        __syncthreads();
        {  // w = phi @ c_vec[b]
          const long cv0 = (long)(m16 + arow) * NU * NC;
          for (int c = aj; c < NC; c += 16) {
            float acc = 0.f;
            for (int u = ulo; u <= uhi; ++u)
              acc += phiL[arow][u] * ldIn(p.c_vec, cv0 + (long)u * NC + c, isF32);
            wL[arow][c] = (bf16)acc;
          }
        }
      }
      __syncthreads();
      {  // ff2 MFMAs: in2 = [xt, h1(t), w], recur h2(t-1)
        f32x4 acc = {0.f, 0.f, 0.f, 0.f};
        int cnt = 0;
        const size_t oX = g ? W2X_K : W2X_J, oA = g ? W2A_K : W2A_J;
        const size_t oW = g ? W2W_K : W2W_J, oH = g ? W2H_K : W2H_J;
        accum_term(acc, cnt, kh, &xtL[0][0], 32, p.W + oX + (size_t)slab * NS,        1,  lr, ko, lane);
        accum_term(acc, cnt, kh, h1L, HSTRIDE, p.W + oA + (size_t)slab * (16 * NS), 16, lr, ko, lane);
        accum_term(acc, cnt, kh, &wL[0][0], 96, p.W + oW + (size_t)slab * (3 * NS),   3,  lr, ko, lane);
        accum_term(acc, cnt, kh, h2L, HSTRIDE, p.W + oH + (size_t)slab * (16 * NS), 16, lr, ko, lane);
        accA[wid][lane] = acc;
      }
      if (slab < 8 && t >= 1) {  // out-head MFMAs for rows (t-1): A = h3(par_p), agent loads
        f32x4 acc = {0.f, 0.f, 0.f, 0.f};
        const unsigned* hg3p = hg3 + par_p * HBUFD + (m16 << 8);
        const bf16* B = p.W + WLIN + (size_t)slab * (16 * NS);
        for (int kb = 0; kb < 16; ++kb) {
          if ((kb & 3) != wid) continue;
          bf16x8 a = ldH8(hg3p, lr, kb * 32 + ko);
          bf16x8 b = *(const bf16x8*)(B + ((size_t)kb * 64 + lane) * 8);
          acc = __builtin_amdgcn_mfma_f32_16x16x32_bf16(a, b, acc, 0, 0, 0);
        }
        accB[wid][lane] = acc;
      }
      __syncthreads();
      {  // ff2 epilogue -> h2(t) via LDS tile
        int ls = tid & 63, r = tid >> 6;
        int s = (slab << 4) + (ls & 15);
        int rowIdx = ((ls >> 4) << 2) + r;
        float jp = accA[0][ls][r] + accA[1][ls][r] + p.bias[1024 + s];
        float kp = accA[2][ls][r] + accA[3][ls][r] + p.bias[1536 + s];
        float ho = (float)h2L[rowIdx * HSTRIDE + s];
        float jj = 1.f / (1.f + __expf(-jp));
        float kk = 1.f / (1.f + __expf(-kp));
        hOutA[rowIdx][ls & 15] = (bf16)(jj * (1.f - ho) + (1.f - kk) * ho);
      }
      if (slab < 8 && t >= 1 && tid < 64) {  // out-head epilogue (plain stores)
        int o = (slab << 4) + (tid & 15);
        if (o < NOUT) {
          float bl = ldIn(p.b_lin, o, isF32);
          int rb = (tid >> 4) << 2;
          for (int r = 0; r < 4; ++r) {
            float v = accB[0][tid][r] + accB[1][tid][r] + accB[2][tid][r] + accB[3][tid][r] + bl;
            long oi = ((long)(m16 + rb + r) * NT + (t - 1)) * NOUT + o;
            if (isF32) ((float*)p.out)[oi] = v; else ((bf16*)p.out)[oi] = (bf16)v;
          }
        }
      }
      __syncthreads();
      if (tid < 128) {  // pack + agent-store h2(t) 16x16 tile
        int row = tid >> 3, c = tid & 7;
        union { unsigned u; unsigned short s[2]; } v;
        union { bf16 b; unsigned short s; } a0, a1;
        a0.b = hOutA[row][2 * c]; a1.b = hOutA[row][2 * c + 1];
        v.s[0] = a0.s; v.s[1] = a1.s;
        __hip_atomic_store(hg2w + par_t * HBUFD + (m16 + row) * 256 + slab * 8 + c, v.u,
                           __ATOMIC_RELAXED, __HIP_MEMORY_SCOPE_AGENT);
      }
      group_barrier(p.bar, m, ++bt);
    }

    // ======== Stage Q: ff3(t) + ff1(t+1) ========
    if (t >= 0) stage_tile(hg2c + par_t * HBUFD + (m16 << 8), (unsigned*)h2L, tid);
    if (t == -1) stage_tile(hg1 + HBUFD + (m16 << 8), (unsigned*)h1L, tid);
    if (t < NT - 1 && tid < 48) {
      int row = tid / 3, d = tid - row * 3;
      xt2L[row][d] = (bf16)ldIn(p.x, ((long)(m16 + row) * NT + (t + 1)) * 3 + d, isF32);
    }
    __syncthreads();
    f32x4 acc3 = {0.f, 0.f, 0.f, 0.f};
    f32x4 acc1 = {0.f, 0.f, 0.f, 0.f};
    if (t >= 0) {  // ff3: in3 = [xt, h2(t), w], recur h3(t-1)  (reuses rnn2 weights)
      int cnt = 0;
      const size_t oX = g ? W2X_K : W2X_J, oA = g ? W2A_K : W2A_J;
      const size_t oW = g ? W2W_K : W2W_J, oH = g ? W2H_K : W2H_J;
      accum_term(acc3, cnt, kh, &xtL[0][0], 32, p.W + oX + (size_t)slab * NS,        1,  lr, ko, lane);
      accum_term(acc3, cnt, kh, h2L, HSTRIDE, p.W + oA + (size_t)slab * (16 * NS), 16, lr, ko, lane);
      accum_term(acc3, cnt, kh, &wL[0][0], 96, p.W + oW + (size_t)slab * (3 * NS),   3,  lr, ko, lane);
      {  // h3(par_p) recur term via agent loads
        const bf16* Bh = p.W + oH + (size_t)slab * (16 * NS);
        const unsigned* hg3p = hg3 + par_p * HBUFD + (m16 << 8);
        for (int kb = 0; kb < 16; ++kb) {
          if (((cnt++) & 1) != kh) continue;
          bf16x8 a = ldH8(hg3p, lr, kb * 32 + ko);
          bf16x8 b = *(const bf16x8*)(Bh + ((size_t)kb * 64 + lane) * 8);
          acc3 = __builtin_amdgcn_mfma_f32_16x16x32_bf16(a, b, acc3, 0, 0, 0);
        }
      }
    }
    if (t < NT - 1) {  // ff1(t+1): in1 = [xt(t+1), w(t)], recur h1(t)
      int cnt = 0;
      const size_t oX = g ? W1X_K : W1X_J, oW = g ? W1W_K : W1W_J, oH = g ? W1H_K : W1H_J;
      accum_term(acc1, cnt, kh, &xt2L[0][0], 32, p.W + oX + (size_t)slab * NS,       1,  lr, ko, lane);
      accum_term(acc1, cnt, kh, &wL[0][0], 96, p.W + oW + (size_t)slab * (3 * NS),   3,  lr, ko, lane);
      accum_term(acc1, cnt, kh, h1L, HSTRIDE, p.W + oH + (size_t)slab * (16 * NS), 16, lr, ko, lane);
    }
    accA[wid][lane] = acc3;
    accB[wid][lane] = acc1;
    __syncthreads();
    {
      int ls = tid & 63, r = tid >> 6;
      int s = (slab << 4) + (ls & 15);
      int rowIdx = ((ls >> 4) << 2) + r;
      if (t >= 0) {  // h3(t)
        float jp = accA[0][ls][r] + accA[1][ls][r] + p.bias[1024 + s];
        float kp = accA[2][ls][r] + accA[3][ls][r] + p.bias[1536 + s];
        union { unsigned u; unsigned short h[2]; } dv;
        dv.u = __hip_atomic_load(hg3 + par_p * HBUFD + (m16 + rowIdx) * 256 + (s >> 1),
                                 __ATOMIC_RELAXED, __HIP_MEMORY_SCOPE_AGENT);
        float ho = (float)us2bf(dv.h[s & 1]);
        float jj = 1.f / (1.f + __expf(-jp));
        float kk = 1.f / (1.f + __expf(-kp));
        hOutA[rowIdx][ls & 15] = (bf16)(jj * (1.f - ho) + (1.f - kk) * ho);
      }
      if (t < NT - 1) {  // h1(t+1)
        float jp = accB[0][ls][r] + accB[1][ls][r] + p.bias[0 + s];
        float kp = accB[2][ls][r] + accB[3][ls][r] + p.bias[512 + s];
        float ho = (float)h1L[rowIdx * HSTRIDE + s];
        float jj = 1.f / (1.f + __expf(-jp));
        float kk = 1.f / (1.f + __expf(-kp));
        hOutB[rowIdx][ls & 15] = (bf16)(jj * (1.f - ho) + (1.f - kk) * ho);
      }
    }
    __syncthreads();
    if (t >= 0 && tid < 128) {       // store h3(t)
      int row = tid >> 3, c = tid & 7;
      union { unsigned u; unsigned short s[2]; } v;
      union { bf16 b; unsigned short s; } a0, a1;
      a0.b = hOutA[row][2 * c]; a1.b = hOutA[row][2 * c + 1];
      v.s[0] = a0.s; v.s[1] = a1.s;
      __hip_atomic_store(hg3w + par_t * HBUFD + (m16 + row) * 256 + slab * 8 + c, v.u,
                         __ATOMIC_RELAXED, __HIP_MEMORY_SCOPE_AGENT);
    }
    if (t < NT - 1 && tid >= 128) {  // store h1(t+1)
      int t2 = tid - 128;
      int row = t2 >> 3, c = t2 & 7;
      union { unsigned u; unsigned short s[2]; } v;
      union { bf16 b; unsigned short s; } a0, a1;
      a0.b = hOutB[row][2 * c]; a1.b = hOutB[row][2 * c + 1];
      v.s[0] = a0.s; v.s[1] = a1.s;
      __hip_atomic_store(hg1w + par_p * HBUFD + (m16 + row) * 256 + slab * 8 + c, v.u,
                         __ATOMIC_RELAXED, __HIP_MEMORY_SCOPE_AGENT);
    }
    group_barrier(p.bar, m, ++bt);
  }

  // final out-head row t = 599 (h3(599) is in parity 1)
  if (slab < 8) {
    f32x4 acc = {0.f, 0.f, 0.f, 0.f};
    const unsigned* hg3p = hg3 + HBUFD + (m16 << 8);
    const bf16* B = p.W + WLIN + (size_t)slab * (16 * NS);
    for (int kb = 0; kb < 16; ++kb) {
      if ((kb & 3) != wid) continue;
      bf16x8 a = ldH8(hg3p, lr, kb * 32 + ko);
      bf16x8 b = *(const bf16x8*)(B + ((size_t)kb * 64 + lane) * 8);
      acc = __builtin_amdgcn_mfma_f32_16x16x32_bf16(a, b, acc, 0, 0, 0);
    }
    accB[wid][lane] = acc;
    __syncthreads();
    if (tid < 64) {
      int o = (slab << 4) + (tid & 15);
      if (o < NOUT) {
        float bl = ldIn(p.b_lin, o, isF32);
        int rb = (tid >> 4) << 2;
        for (int r = 0; r < 4; ++r) {
          float v = accB[0][tid][r] + accB[1][tid][r] + accB[2][tid][r] + accB[3][tid][r] + bl;
          long oi = ((long)(m16 + rb + r) * NT + (NT - 1)) * NOUT + o;
          if (isF32) ((float*)p.out)[oi] = v; else ((bf16*)p.out)[oi] = (bf16)v;
        }
      }
    }
  }
}

extern "C" void kernel_launch(void* const* d_in, const int* in_sizes, int n_in,
                              void* d_out, int out_size, void* d_ws, size_t ws_size,
                              hipStream_t stream) {
  (void)in_sizes; (void)n_in; (void)out_size; (void)ws_size;

  bf16*  wsW  = (bf16*)d_ws;
  float* bias = (float*)((char*)d_ws + BIAS_BYTE_OFF);
  bf16*  h1   = (bf16*)((char*)d_ws + H_BYTE_OFF);
  bf16*  h2   = h1 + 2 * HBUF;
  bf16*  h3   = h2 + 2 * HBUF;
  int*   flag = (int*)((char*)d_ws + FLAG_BYTE_OFF);
  int*   bar  = (int*)((char*)d_ws + BAR_BYTE_OFF);

  sniff_kernel<<<1, 256, 0, stream>>>((const unsigned short*)d_in[4], flag);

  prep_kernel<<<dim3(1024, 18), 256, 0, stream>>>(
      d_in[2], d_in[4], d_in[6], d_in[8], d_in[10], d_in[12], d_in[14], d_in[16],
      d_in[18], d_in[20],
      d_in[3], d_in[5], d_in[7], d_in[9], d_in[11], d_in[13], d_in[15], d_in[17],
      wsW, bias, h1, h2, h3, bar, flag);

  KParams kp;
  kp.x = d_in[0]; kp.c_vec = d_in[1]; kp.b_win = d_in[19]; kp.b_lin = d_in[21];
  kp.W = wsW; kp.bias = bias;
  kp.h1 = h1; kp.h2 = h2; kp.h3 = h3;
  kp.out = d_out;
  kp.flag = flag;
  kp.bar = bar;

  scan_kernel<<<256, 256, 0, stream>>>(kp);
}

// Round 6
// 18757.518 us; speedup vs baseline: 3.9918x; 1.6927x over previous
//
#include <hip/hip_runtime.h>
#include <hip/hip_bf16.h>

typedef __bf16 bf16;
typedef __bf16 bf16x8 __attribute__((ext_vector_type(8)));
typedef float  f32x4  __attribute__((ext_vector_type(4)));

#define AS1 __attribute__((address_space(1)))
#define AS3 __attribute__((address_space(3)))

#define NT   600
#define NB   128
#define NS   512
#define NU   96
#define NK   10
#define NC   80
#define NOUT 121

// packed-weight element offsets in ws (bf16 elements), layout [slab][kb][lane][8]
#define W1X_J 0
#define W1W_J 16384
#define W1H_J 65536
#define W1X_K 327680
#define W1W_K 344064
#define W1H_K 393216
#define W2X_J 655360
#define W2W_J 671744
#define W2A_J 720896
#define W2H_J 983040
#define W2X_K 1245184
#define W2W_K 1261568
#define W2A_K 1310720
#define W2H_K 1572864
#define WWIN  1835008
#define WLIN  1851392

#define BIAS_BYTE_OFF 3833856         // 2048 floats: [b1j|b1k|b2j|b2k]
#define H_BYTE_OFF    3842048         // h1[2][128][512], h2..., h3... bf16
#define HBUF 65536                    // bf16 elements per parity buffer
#define FLAG_BYTE_OFF 4659200         // int isF32
#define BAR_BYTE_OFF  4659264         // int bar[1024]; per group g*64: cnt@0 ep@8 dcnt@16 dep@24 xmask@32

#define HSTRIDE 520                   // LDS h-tile row stride in bf16 (1040B: 16B-aligned, 4-bank row skew)

// cache-policy aux for global_load_lds (gfx940+ CPol): SC0=bit0, SC1=bit4
#define AUX_SC0   1
#define AUX_SC0S1 17

__device__ __forceinline__ float ldIn(const void* q, long i, int isF32) {
  if (isF32) return ((const float*)q)[i];
  return (float)((const bf16*)q)[i];
}

struct KParams {
  const void* x;       // [128][600][3]
  const void* c_vec;   // [128][96][80]
  const void* b_win;   // [30]
  const void* b_lin;   // [121]
  const bf16* W;       // packed weights base
  const float* bias;   // [4*512]
  bf16* h1; bf16* h2; bf16* h3;  // [2][128][512] each
  void* out;           // [128*600][121]
  const int* flag;
  int* bar;
};

// ---- async global->LDS tile stage: 16 rows x 512 bf16, one 1KB DMA per row ----
template <int AUX>
__device__ __forceinline__ void stage_tile_async(const bf16* g, bf16* lds, int tid) {
  const int w = tid >> 6, lane = tid & 63;
#pragma unroll
  for (int r = 0; r < 4; ++r) {
    const int row = (w << 2) + r;
    __builtin_amdgcn_global_load_lds(
        (const AS1 void*)(g + (size_t)row * NS + (size_t)lane * 8),
        (AS3 void*)(lds + (size_t)row * HSTRIDE), 16, 0, AUX);
  }
}

// ---- per-m-group barrier: 32 arrivals, monotonic epoch, agent scope (proven) ----
__device__ __forceinline__ void group_barrier(int* gb, int target) {
  __syncthreads();   // drains this WG's vmem (h stores) before the arrive
  if (threadIdx.x == 0) {
    if ((__hip_atomic_fetch_add(gb, 1, __ATOMIC_RELAXED, __HIP_MEMORY_SCOPE_AGENT) & 31) == 31)
      __hip_atomic_fetch_add(gb + 8, 1, __ATOMIC_RELAXED, __HIP_MEMORY_SCOPE_AGENT);
    while (__hip_atomic_load(gb + 8, __ATOMIC_RELAXED, __HIP_MEMORY_SCOPE_AGENT) < target)
      __builtin_amdgcn_s_sleep(1);
  }
  __syncthreads();
  __atomic_signal_fence(__ATOMIC_ACQ_REL);
}

__device__ __forceinline__ void storeH(unsigned* dst, unsigned v, bool fast) {
  if (fast) *dst = v;   // plain store -> local L2 (same-XCD consumers read with sc0)
  else __hip_atomic_store(dst, v, __ATOMIC_RELAXED, __HIP_MEMORY_SCOPE_AGENT);
}

// ---------------- sniff: decide f32 vs bf16 input encoding ----------------
__global__ void sniff_kernel(const unsigned short* w, int* flag) {
  __shared__ int cnt;
  if (threadIdx.x == 0) cnt = 0;
  __syncthreads();
  int c = 0;
  for (int i = threadIdx.x; i < 8192; i += 256) {
    unsigned e = (w[2 * i] >> 7) & 0xFF;
    if (e == 0xFF || e < 96) c++;
  }
  atomicAdd(&cnt, c);
  __syncthreads();
  if (threadIdx.x == 0) *flag = (cnt > 512) ? 1 : 0;
}

// ---------------- prep: repack weights + zero state + zero barriers ----------------
__global__ void prep_kernel(const void* Wjx1, const void* Wjh1, const void* Wkx1, const void* Wkh1,
                            const void* Wjx2, const void* Wjh2, const void* Wkx2, const void* Wkh2,
                            const void* Wwin, const void* Wlin,
                            const void* bjx1, const void* bjh1, const void* bkx1, const void* bkh1,
                            const void* bjx2, const void* bjh2, const void* bkx2, const void* bkh2,
                            bf16* W, float* bias,
                            bf16* h1, bf16* h2, bf16* h3, int* bar,
                            const int* flag) {
  const int isF32 = *flag;
  const int r = blockIdx.y;
  const int e = blockIdx.x * 256 + threadIdx.x;
  if (r == 16) {
    if (e < 512) {
      bias[e]        = ldIn(bjx1, e, isF32) + ldIn(bjh1, e, isF32);
      bias[512 + e]  = ldIn(bkx1, e, isF32) + ldIn(bkh1, e, isF32);
      bias[1024 + e] = ldIn(bjx2, e, isF32) + ldIn(bjh2, e, isF32);
      bias[1536 + e] = ldIn(bkx2, e, isF32) + ldIn(bkh2, e, isF32);
    }
    return;
  }
  if (r == 17) {
    if (e < HBUF) {
      h1[HBUF + e] = (bf16)0.f;
      h2[HBUF + e] = (bf16)0.f;
      h3[HBUF + e] = (bf16)0.f;
    }
    if (e < 1024) bar[e] = 0;
    return;
  }
  const int   row0s[16]  = {0,3,0, 0,3,0, 0,515,3,0, 0,515,3,0, 0,0};
  const int   klens[16]  = {3,80,512, 3,80,512, 3,80,512,512, 3,80,512,512, 512,512};
  const int   kpads[16]  = {32,96,512, 32,96,512, 32,96,512,512, 32,96,512,512, 512,512};
  const int   cpads[16]  = {512,512,512, 512,512,512, 512,512,512,512, 512,512,512,512, 32,128};
  const int   nsrcs[16]  = {512,512,512, 512,512,512, 512,512,512,512, 512,512,512,512, 30,121};
  const long  offs[16]   = {W1X_J,W1W_J,W1H_J, W1X_K,W1W_K,W1H_K,
                            W2X_J,W2W_J,W2A_J,W2H_J, W2X_K,W2W_K,W2A_K,W2H_K, WWIN,WLIN};
  const void* srcs[16]   = {Wjx1,Wjx1,Wjh1, Wkx1,Wkx1,Wkh1,
                            Wjx2,Wjx2,Wjx2,Wjh2, Wkx2,Wkx2,Wkx2,Wkh2, Wwin,Wlin};
  const int Kpad = kpads[r], cp = cpads[r];
  const long tot = (long)Kpad * cp;
  if (e >= tot) return;
  const int j    = e & 7;
  const int lane = (e >> 3) & 63;
  const int rest = e >> 9;
  const int kbs  = Kpad >> 5;
  const int kb   = rest % kbs;
  const int slab = rest / kbs;
  const int col  = slab * 16 + (lane & 15);
  const int k    = kb * 32 + ((lane >> 4) << 3) + j;
  const int Klen = klens[r], row0 = row0s[r], N = nsrcs[r];
  bf16 v = (bf16)0.f;
  if (k < Klen && col < N) v = (bf16)ldIn(srcs[r], (long)(row0 + k) * N + col, isF32);
  W[offs[r] + e] = v;
}

// ---------------- shared MFMA helper ----------------
__device__ __forceinline__ void accum_term(f32x4& acc, int& cnt, int kh,
    const bf16* Arow, int astride, const bf16* B, int kbs,
    int lr, int ko, int lane) {
  for (int kb = 0; kb < kbs; ++kb) {
    if (((cnt++) & 1) != kh) continue;
    bf16x8 a = *(const bf16x8*)(Arow + (size_t)lr * astride + kb * 32 + ko);
    bf16x8 b = *(const bf16x8*)(B + ((size_t)kb * 64 + lane) * 8);
    acc = __builtin_amdgcn_mfma_f32_16x16x32_bf16(a, b, acc, 0, 0, 0);
  }
}

// ================= persistent scan kernel =================
__global__ __launch_bounds__(256) void scan_kernel(KParams p) {
  const int isF32 = *p.flag;
  const int tid  = threadIdx.x;
  const int wid  = tid >> 6;
  const int lane = tid & 63;
  const int wg   = blockIdx.x;       // 256 WGs, 1 per CU
  const int m    = wg & 7;           // 8 m-groups; round-robin maps a group onto one XCD
  const int slab = wg >> 3;          // 32 col-slabs (16 cols each)
  const int m16  = m << 4;
  const int lr   = lane & 15;
  const int ko   = (lane >> 4) << 3;
  const int g    = wid >> 1;         // gate (0=j,1=k)
  const int kh   = wid & 1;          // K-half

  unsigned* hg1w = (unsigned*)p.h1;
  unsigned* hg2w = (unsigned*)p.h2;
  unsigned* hg3w = (unsigned*)p.h3;

  __shared__ alignas(16) bf16 h1L[16 * HSTRIDE];
  __shared__ alignas(16) bf16 h2L[16 * HSTRIDE];
  __shared__ alignas(16) bf16 h3L[16 * HSTRIDE];
  __shared__ alignas(16) bf16 xtL[16][32];
  __shared__ alignas(16) bf16 xt2L[16][32];
  __shared__ alignas(16) bf16 wL[16][96];
  __shared__ float kgL[16][32];
  __shared__ float kapL[16][NK];
  __shared__ float alphaL[16][NK];
  __shared__ float betaL[16][NK];
  __shared__ float wloL[16][16];
  __shared__ float whiL[16][16];
  __shared__ int   winL[16][2];
  __shared__ float phiL[16][NU];
  __shared__ f32x4 accA[4][64];
  __shared__ f32x4 accB[4][64];
  __shared__ bf16  hOutA[16][16];
  __shared__ bf16  hOutB[16][16];

  for (int i = tid; i < 16 * 32; i += 256) { (&xtL[0][0])[i] = (bf16)0.f; (&xt2L[0][0])[i] = (bf16)0.f; }
  for (int i = tid; i < 16 * 96; i += 256) (&wL[0][0])[i] = (bf16)0.f;
  for (int i = tid; i < 16 * NK; i += 256) (&kapL[0][0])[i] = 0.f;
  __syncthreads();

  // ---- runtime XCD-locality detection (per launch; both paths numerically identical) ----
  int* gb = p.bar + m * 64;
  {
    int xcc = __builtin_amdgcn_s_getreg((3 << 11) | (0 << 6) | 20) & 31;  // HW_REG_XCC_ID
    if (tid == 0) {
      __hip_atomic_fetch_or((unsigned*)(gb + 32), 1u << xcc,
                            __ATOMIC_RELAXED, __HIP_MEMORY_SCOPE_AGENT);
      __threadfence();   // one-time: ensure the OR is globally visible before arrive
      if ((__hip_atomic_fetch_add(gb + 16, 1, __ATOMIC_RELAXED, __HIP_MEMORY_SCOPE_AGENT) & 31) == 31)
        __hip_atomic_fetch_add(gb + 24, 1, __ATOMIC_RELAXED, __HIP_MEMORY_SCOPE_AGENT);
      while (__hip_atomic_load(gb + 24, __ATOMIC_RELAXED, __HIP_MEMORY_SCOPE_AGENT) < 1)
        __builtin_amdgcn_s_sleep(1);
    }
    __syncthreads();
  }
  const unsigned msk = __hip_atomic_load((unsigned*)(gb + 32),
                                         __ATOMIC_RELAXED, __HIP_MEMORY_SCOPE_AGENT);
  const bool fast = (msk & (msk - 1)) == 0;   // single-XCD group -> L2-local exchange

  int bt = 0;
  for (int t = -1; t < NT; ++t) {
    const int par_t = t & 1;        // (-1)&1 == 1
    const int par_p = (t + 1) & 1;

    if (t >= 0) {
      // ======== Stage P: attention(t) + ff2(t) + out-head(t-1) ========
      {
        const bf16* g1 = p.h1 + (size_t)par_t * HBUF + (size_t)m16 * NS;
        const bf16* g2 = p.h2 + (size_t)par_p * HBUF + (size_t)m16 * NS;
        const bf16* g3 = p.h3 + (size_t)par_p * HBUF + (size_t)m16 * NS;
        if (fast) {
          stage_tile_async<AUX_SC0>(g1, h1L, tid);
          stage_tile_async<AUX_SC0>(g2, h2L, tid);
          stage_tile_async<AUX_SC0>(g3, h3L, tid);
        } else {
          stage_tile_async<AUX_SC0S1>(g1, h1L, tid);
          stage_tile_async<AUX_SC0S1>(g2, h2L, tid);
          stage_tile_async<AUX_SC0S1>(g3, h3L, tid);
        }
      }
      if (tid < 48) {
        int row = tid / 3, d = tid - row * 3;
        xtL[row][d] = (bf16)ldIn(p.x, ((long)(m16 + row) * NT + t) * 3 + d, isF32);
      }
      __syncthreads();   // drains the DMA (vmcnt) + xt writes
      {  // kg = h1(t) @ W_win via MFMA
        int n2 = wid & 1, kh2 = wid >> 1;
        f32x4 acc = {0.f, 0.f, 0.f, 0.f};
        const bf16* B = p.W + WWIN + (size_t)n2 * (16 * NS);
        for (int kb = 0; kb < 16; ++kb) {
          if ((kb & 1) != kh2) continue;
          bf16x8 a = *(const bf16x8*)(h1L + (size_t)lr * HSTRIDE + kb * 32 + ko);
          bf16x8 b = *(const bf16x8*)(B + ((size_t)kb * 64 + lane) * 8);
          acc = __builtin_amdgcn_mfma_f32_16x16x32_bf16(a, b, acc, 0, 0, 0);
        }
        accA[wid][lane] = acc;
      }
      __syncthreads();
      if (tid < 128) {  // kg epilogue
        int ls = tid & 63, n2s = tid >> 6;
        int o = n2s * 16 + (ls & 15);
        if (o < 30) {
          int rowb = (ls >> 4) << 2;
          for (int r = 0; r < 4; ++r)
            kgL[rowb + r][o] = accA[n2s][ls][r] + accA[n2s + 2][ls][r] + ldIn(p.b_win, o, isF32);
        }
      }
      __syncthreads();
      {  // attention scalars (kap in LDS across steps; same thread owns same slot)
        int arow = tid >> 4, aj = tid & 15;
        if (aj < NK) {
          float ah = kgL[arow][aj];
          float be = expf(kgL[arow][NK + aj]);
          float dk = expf(kgL[arow][2 * NK + aj]);
          float al = expf(ah);
          float kap = kapL[arow][aj] + dk;
          kapL[arow][aj] = kap;
          alphaL[arow][aj] = al;
          betaL[arow][aj] = be;
          float arg = (ah + 18.42f) / be;
          float lo, hi;
          if (arg > 0.f) { float R = sqrtf(arg); lo = kap - R; hi = kap + R; }
          else           { lo = 1e30f; hi = -1e30f; }
          wloL[arow][aj] = lo; whiL[arow][aj] = hi;
        } else { wloL[arow][aj] = 1e30f; whiL[arow][aj] = -1e30f; }
        __syncthreads();
        if (aj == 0) {
          float lo = 1e30f, hi = -1e30f;
          for (int k2 = 0; k2 < NK; ++k2) { lo = fminf(lo, wloL[arow][k2]); hi = fmaxf(hi, whiL[arow][k2]); }
          int ulo = (lo <= 0.f) ? 0 : ((lo > 95.f) ? 96 : (int)floorf(lo));
          int uhi = (hi >= 95.f) ? 95 : ((hi < 0.f) ? -1 : (int)ceilf(hi));
          winL[arow][0] = ulo; winL[arow][1] = uhi;
        }
        __syncthreads();
        const int ulo = winL[arow][0], uhi = winL[arow][1];
        for (int u = ulo + aj; u <= uhi; u += 16) {
          float s = 0.f, uf = (float)u;
          for (int k2 = 0; k2 < NK; ++k2) {
            float d = kapL[arow][k2] - uf;
            s += alphaL[arow][k2] * __expf(-betaL[arow][k2] * d * d);
          }
          phiL[arow][u] = s;
        }
        __syncthreads();
        if (isF32) {  // w = phi @ c_vec[b], vectorized x4; per-c u-order identical to scalar
          const float* cv = (const float*)p.c_vec + (long)(m16 + arow) * NU * NC;
          for (int ch = aj; ch < 20; ch += 16) {
            float a0 = 0.f, a1 = 0.f, a2 = 0.f, a3 = 0.f;
            for (int u = ulo; u <= uhi; ++u) {
              const float* q = cv + (long)u * NC + (ch << 2);
              float ph = phiL[arow][u];
              a0 += ph * q[0]; a1 += ph * q[1]; a2 += ph * q[2]; a3 += ph * q[3];
            }
            wL[arow][(ch << 2) + 0] = (bf16)a0;
            wL[arow][(ch << 2) + 1] = (bf16)a1;
            wL[arow][(ch << 2) + 2] = (bf16)a2;
            wL[arow][(ch << 2) + 3] = (bf16)a3;
          }
        } else {
          const long cv0 = (long)(m16 + arow) * NU * NC;
          for (int c = aj; c < NC; c += 16) {
            float acc = 0.f;
            for (int u = ulo; u <= uhi; ++u)
              acc += phiL[arow][u] * ldIn(p.c_vec, cv0 + (long)u * NC + c, isF32);
            wL[arow][c] = (bf16)acc;
          }
        }
      }
      __syncthreads();
      {  // ff2 MFMAs: in2 = [xt, h1(t), w], recur h2(t-1)
        f32x4 acc = {0.f, 0.f, 0.f, 0.f};
        int cnt = 0;
        const size_t oX = g ? W2X_K : W2X_J, oA = g ? W2A_K : W2A_J;
        const size_t oW = g ? W2W_K : W2W_J, oH = g ? W2H_K : W2H_J;
        accum_term(acc, cnt, kh, &xtL[0][0], 32, p.W + oX + (size_t)slab * NS,        1,  lr, ko, lane);
        accum_term(acc, cnt, kh, h1L, HSTRIDE, p.W + oA + (size_t)slab * (16 * NS), 16, lr, ko, lane);
        accum_term(acc, cnt, kh, &wL[0][0], 96, p.W + oW + (size_t)slab * (3 * NS),   3,  lr, ko, lane);
        accum_term(acc, cnt, kh, h2L, HSTRIDE, p.W + oH + (size_t)slab * (16 * NS), 16, lr, ko, lane);
        accA[wid][lane] = acc;
      }
      if (slab < 8 && t >= 1) {  // out-head MFMAs for rows (t-1): A = h3(par_p) from LDS
        f32x4 acc = {0.f, 0.f, 0.f, 0.f};
        const bf16* B = p.W + WLIN + (size_t)slab * (16 * NS);
        for (int kb = 0; kb < 16; ++kb) {
          if ((kb & 3) != wid) continue;
          bf16x8 a = *(const bf16x8*)(h3L + (size_t)lr * HSTRIDE + kb * 32 + ko);
          bf16x8 b = *(const bf16x8*)(B + ((size_t)kb * 64 + lane) * 8);
          acc = __builtin_amdgcn_mfma_f32_16x16x32_bf16(a, b, acc, 0, 0, 0);
        }
        accB[wid][lane] = acc;
      }
      __syncthreads();
      {  // ff2 epilogue -> h2(t)
        int ls = tid & 63, r = tid >> 6;
        int s = (slab << 4) + (ls & 15);
        int rowIdx = ((ls >> 4) << 2) + r;
        float jp = accA[0][ls][r] + accA[1][ls][r] + p.bias[1024 + s];
        float kp = accA[2][ls][r] + accA[3][ls][r] + p.bias[1536 + s];
        float ho = (float)h2L[rowIdx * HSTRIDE + s];
        float jj = 1.f / (1.f + __expf(-jp));
        float kk = 1.f / (1.f + __expf(-kp));
        hOutA[rowIdx][ls & 15] = (bf16)(jj * (1.f - ho) + (1.f - kk) * ho);
      }
      if (slab < 8 && t >= 1 && tid < 64) {  // out-head epilogue
        int o = (slab << 4) + (tid & 15);
        if (o < NOUT) {
          float bl = ldIn(p.b_lin, o, isF32);
          int rb = (tid >> 4) << 2;
          for (int r = 0; r < 4; ++r) {
            float v = accB[0][tid][r] + accB[1][tid][r] + accB[2][tid][r] + accB[3][tid][r] + bl;
            long oi = ((long)(m16 + rb + r) * NT + (t - 1)) * NOUT + o;
            if (isF32) ((float*)p.out)[oi] = v; else ((bf16*)p.out)[oi] = (bf16)v;
          }
        }
      }
      __syncthreads();
      if (tid < 128) {  // pack + store h2(t) 16x16 tile
        int row = tid >> 3, c = tid & 7;
        union { unsigned u; unsigned short s[2]; } v;
        union { bf16 b; unsigned short s; } a0, a1;
        a0.b = hOutA[row][2 * c]; a1.b = hOutA[row][2 * c + 1];
        v.s[0] = a0.s; v.s[1] = a1.s;
        storeH(hg2w + (size_t)par_t * (HBUF / 2) + (m16 + row) * 256 + slab * 8 + c, v.u, fast);
      }
      group_barrier(gb, ++bt);
    }

    // ======== Stage Q: ff3(t) + ff1(t+1) ========
    if (t >= 0) {
      const bf16* g2 = p.h2 + (size_t)par_t * HBUF + (size_t)m16 * NS;
      if (fast) stage_tile_async<AUX_SC0>(g2, h2L, tid);
      else      stage_tile_async<AUX_SC0S1>(g2, h2L, tid);
    }
    if (t == -1) {
      const bf16* g1 = p.h1 + (size_t)HBUF + (size_t)m16 * NS;   // parity 1 zeros
      if (fast) stage_tile_async<AUX_SC0>(g1, h1L, tid);
      else      stage_tile_async<AUX_SC0S1>(g1, h1L, tid);
    }
    if (t < NT - 1 && tid < 48) {
      int row = tid / 3, d = tid - row * 3;
      xt2L[row][d] = (bf16)ldIn(p.x, ((long)(m16 + row) * NT + (t + 1)) * 3 + d, isF32);
    }
    __syncthreads();
    f32x4 acc3 = {0.f, 0.f, 0.f, 0.f};
    f32x4 acc1 = {0.f, 0.f, 0.f, 0.f};
    if (t >= 0) {  // ff3: in3 = [xt, h2(t), w], recur h3(t-1)  (reuses rnn2 weights)
      int cnt = 0;
      const size_t oX = g ? W2X_K : W2X_J, oA = g ? W2A_K : W2A_J;
      const size_t oW = g ? W2W_K : W2W_J, oH = g ? W2H_K : W2H_J;
      accum_term(acc3, cnt, kh, &xtL[0][0], 32, p.W + oX + (size_t)slab * NS,        1,  lr, ko, lane);
      accum_term(acc3, cnt, kh, h2L, HSTRIDE, p.W + oA + (size_t)slab * (16 * NS), 16, lr, ko, lane);
      accum_term(acc3, cnt, kh, &wL[0][0], 96, p.W + oW + (size_t)slab * (3 * NS),   3,  lr, ko, lane);
      accum_term(acc3, cnt, kh, h3L, HSTRIDE, p.W + oH + (size_t)slab * (16 * NS), 16, lr, ko, lane);
    }
    if (t < NT - 1) {  // ff1(t+1): in1 = [xt(t+1), w(t)], recur h1(t)
      int cnt = 0;
      const size_t oX = g ? W1X_K : W1X_J, oW = g ? W1W_K : W1W_J, oH = g ? W1H_K : W1H_J;
      accum_term(acc1, cnt, kh, &xt2L[0][0], 32, p.W + oX + (size_t)slab * NS,       1,  lr, ko, lane);
      accum_term(acc1, cnt, kh, &wL[0][0], 96, p.W + oW + (size_t)slab * (3 * NS),   3,  lr, ko, lane);
      accum_term(acc1, cnt, kh, h1L, HSTRIDE, p.W + oH + (size_t)slab * (16 * NS), 16, lr, ko, lane);
    }
    accA[wid][lane] = acc3;
    accB[wid][lane] = acc1;
    __syncthreads();
    {
      int ls = tid & 63, r = tid >> 6;
      int s = (slab << 4) + (ls & 15);
      int rowIdx = ((ls >> 4) << 2) + r;
      if (t >= 0) {  // h3(t)
        float jp = accA[0][ls][r] + accA[1][ls][r] + p.bias[1024 + s];
        float kp = accA[2][ls][r] + accA[3][ls][r] + p.bias[1536 + s];
        float ho = (float)h3L[rowIdx * HSTRIDE + s];
        float jj = 1.f / (1.f + __expf(-jp));
        float kk = 1.f / (1.f + __expf(-kp));
        hOutA[rowIdx][ls & 15] = (bf16)(jj * (1.f - ho) + (1.f - kk) * ho);
      }
      if (t < NT - 1) {  // h1(t+1)
        float jp = accB[0][ls][r] + accB[1][ls][r] + p.bias[0 + s];
        float kp = accB[2][ls][r] + accB[3][ls][r] + p.bias[512 + s];
        float ho = (float)h1L[rowIdx * HSTRIDE + s];
        float jj = 1.f / (1.f + __expf(-jp));
        float kk = 1.f / (1.f + __expf(-kp));
        hOutB[rowIdx][ls & 15] = (bf16)(jj * (1.f - ho) + (1.f - kk) * ho);
      }
    }
    __syncthreads();
    if (t >= 0 && tid < 128) {       // store h3(t)
      int row = tid >> 3, c = tid & 7;
      union { unsigned u; unsigned short s[2]; } v;
      union { bf16 b; unsigned short s; } a0, a1;
      a0.b = hOutA[row][2 * c]; a1.b = hOutA[row][2 * c + 1];
      v.s[0] = a0.s; v.s[1] = a1.s;
      storeH(hg3w + (size_t)par_t * (HBUF / 2) + (m16 + row) * 256 + slab * 8 + c, v.u, fast);
    }
    if (t < NT - 1 && tid >= 128) {  // store h1(t+1)
      int t2 = tid - 128;
      int row = t2 >> 3, c = t2 & 7;
      union { unsigned u; unsigned short s[2]; } v;
      union { bf16 b; unsigned short s; } a0, a1;
      a0.b = hOutB[row][2 * c]; a1.b = hOutB[row][2 * c + 1];
      v.s[0] = a0.s; v.s[1] = a1.s;
      storeH(hg1w + (size_t)par_p * (HBUF / 2) + (m16 + row) * 256 + slab * 8 + c, v.u, fast);
    }
    group_barrier(gb, ++bt);
  }

  // final out-head row t = 599 (h3(599) is in parity 1)
  if (slab < 8) {
    const bf16* g3 = p.h3 + (size_t)HBUF + (size_t)m16 * NS;
    if (fast) stage_tile_async<AUX_SC0>(g3, h3L, tid);
    else      stage_tile_async<AUX_SC0S1>(g3, h3L, tid);
    __syncthreads();
    f32x4 acc = {0.f, 0.f, 0.f, 0.f};
    const bf16* B = p.W + WLIN + (size_t)slab * (16 * NS);
    for (int kb = 0; kb < 16; ++kb) {
      if ((kb & 3) != wid) continue;
      bf16x8 a = *(const bf16x8*)(h3L + (size_t)lr * HSTRIDE + kb * 32 + ko);
      bf16x8 b = *(const bf16x8*)(B + ((size_t)kb * 64 + lane) * 8);
      acc = __builtin_amdgcn_mfma_f32_16x16x32_bf16(a, b, acc, 0, 0, 0);
    }
    accB[wid][lane] = acc;
    __syncthreads();
    if (tid < 64) {
      int o = (slab << 4) + (tid & 15);
      if (o < NOUT) {
        float bl = ldIn(p.b_lin, o, isF32);
        int rb = (tid >> 4) << 2;
        for (int r = 0; r < 4; ++r) {
          float v = accB[0][tid][r] + accB[1][tid][r] + accB[2][tid][r] + accB[3][tid][r] + bl;
          long oi = ((long)(m16 + rb + r) * NT + (NT - 1)) * NOUT + o;
          if (isF32) ((float*)p.out)[oi] = v; else ((bf16*)p.out)[oi] = (bf16)v;
        }
      }
    }
  }
}

extern "C" void kernel_launch(void* const* d_in, const int* in_sizes, int n_in,
                              void* d_out, int out_size, void* d_ws, size_t ws_size,
                              hipStream_t stream) {
  (void)in_sizes; (void)n_in; (void)out_size; (void)ws_size;

  bf16*  wsW  = (bf16*)d_ws;
  float* bias = (float*)((char*)d_ws + BIAS_BYTE_OFF);
  bf16*  h1   = (bf16*)((char*)d_ws + H_BYTE_OFF);
  bf16*  h2   = h1 + 2 * HBUF;
  bf16*  h3   = h2 + 2 * HBUF;
  int*   flag = (int*)((char*)d_ws + FLAG_BYTE_OFF);
  int*   bar  = (int*)((char*)d_ws + BAR_BYTE_OFF);

  sniff_kernel<<<1, 256, 0, stream>>>((const unsigned short*)d_in[4], flag);

  prep_kernel<<<dim3(1024, 18), 256, 0, stream>>>(
      d_in[2], d_in[4], d_in[6], d_in[8], d_in[10], d_in[12], d_in[14], d_in[16],
      d_in[18], d_in[20],
      d_in[3], d_in[5], d_in[7], d_in[9], d_in[11], d_in[13], d_in[15], d_in[17],
      wsW, bias, h1, h2, h3, bar, flag);

  KParams kp;
  kp.x = d_in[0]; kp.c_vec = d_in[1]; kp.b_win = d_in[19]; kp.b_lin = d_in[21];
  kp.W = wsW; kp.bias = bias;
  kp.h1 = h1; kp.h2 = h2; kp.h3 = h3;
  kp.out = d_out;
  kp.flag = flag;
  kp.bar = bar;

  scan_kernel<<<256, 256, 0, stream>>>(kp);
}

// Round 7
// 11739.351 us; speedup vs baseline: 6.3782x; 1.5978x over previous
//
#include <hip/hip_runtime.h>
#include <hip/hip_bf16.h>

typedef __bf16 bf16;
typedef __bf16 bf16x8 __attribute__((ext_vector_type(8)));
typedef float  f32x4  __attribute__((ext_vector_type(4)));

#define AS1 __attribute__((address_space(1)))
#define AS3 __attribute__((address_space(3)))

#define NT   600
#define NB   128
#define NS   512
#define NU   96
#define NK   10
#define NC   80
#define NOUT 121

// packed-weight element offsets in ws (bf16 elements), layout [slab][kb][lane][8]
#define W1X_J 0
#define W1W_J 16384
#define W1H_J 65536
#define W1X_K 327680
#define W1W_K 344064
#define W1H_K 393216
#define W2X_J 655360
#define W2W_J 671744
#define W2A_J 720896
#define W2H_J 983040
#define W2X_K 1245184
#define W2W_K 1261568
#define W2A_K 1310720
#define W2H_K 1572864
#define WWIN  1835008
#define WLIN  1851392

#define BIAS_BYTE_OFF 3833856         // 2048 floats: [b1j|b1k|b2j|b2k]
#define H_BYTE_OFF    3842048         // h1[2][128][512], h2..., h3... bf16
#define HBUF 65536                    // bf16 elements per parity buffer
#define FLAG_BYTE_OFF 4659200         // int isF32
#define BAR_BYTE_OFF  4659264         // int bar[1024]; per group g*64: cnt@0 ep@8 dcnt@16 dep@24 xmask@32

#define HSTRIDE 520                   // LDS h-tile row stride in bf16 (1040B: 16B-aligned, bank skew)

// cache-policy aux for global_load_lds (gfx940+ CPol): SC0=bit0, SC1=bit4
#define AUX_SC0   1
#define AUX_SC0S1 17

__device__ __forceinline__ float ldIn(const void* q, long i, int isF32) {
  if (isF32) return ((const float*)q)[i];
  return (float)((const bf16*)q)[i];
}

struct KParams {
  const void* x;       // [128][600][3]
  const void* c_vec;   // [128][96][80]
  const void* b_win;   // [30]
  const void* b_lin;   // [121]
  const bf16* W;       // packed weights base
  const float* bias;   // [4*512]
  bf16* h1; bf16* h2; bf16* h3;  // [2][128][512] each
  void* out;           // [128*600][121]
  const int* flag;
  int* bar;
};

// ---- async global->LDS tile stage: 16 rows x 512 bf16, one 1KB DMA per row ----
template <int AUX>
__device__ __forceinline__ void stage_tile_async(const bf16* g, bf16* lds, int tid) {
  const int w = tid >> 6, lane = tid & 63;
#pragma unroll
  for (int r = 0; r < 4; ++r) {
    const int row = (w << 2) + r;
    __builtin_amdgcn_global_load_lds(
        (const AS1 void*)(g + (size_t)row * NS + (size_t)lane * 8),
        (AS3 void*)(lds + (size_t)row * HSTRIDE), 16, 0, AUX);
  }
}

// ---- per-m-group barrier: 32 arrivals, monotonic epoch, agent scope (proven) ----
__device__ __forceinline__ void group_barrier(int* gb, int target) {
  __syncthreads();   // drains this WG's vmem (h stores) before the arrive
  if (threadIdx.x == 0) {
    if ((__hip_atomic_fetch_add(gb, 1, __ATOMIC_RELAXED, __HIP_MEMORY_SCOPE_AGENT) & 31) == 31)
      __hip_atomic_fetch_add(gb + 8, 1, __ATOMIC_RELAXED, __HIP_MEMORY_SCOPE_AGENT);
    while (__hip_atomic_load(gb + 8, __ATOMIC_RELAXED, __HIP_MEMORY_SCOPE_AGENT) < target)
      __builtin_amdgcn_s_sleep(1);
  }
  __syncthreads();
  __atomic_signal_fence(__ATOMIC_ACQ_REL);
}

__device__ __forceinline__ void storeH(unsigned* dst, unsigned v, bool fast) {
  if (fast) *dst = v;   // plain store -> local L2 (same-XCD consumers read with sc0)
  else __hip_atomic_store(dst, v, __ATOMIC_RELAXED, __HIP_MEMORY_SCOPE_AGENT);
}

// ---------------- sniff: decide f32 vs bf16 input encoding ----------------
__global__ void sniff_kernel(const unsigned short* w, int* flag) {
  __shared__ int cnt;
  if (threadIdx.x == 0) cnt = 0;
  __syncthreads();
  int c = 0;
  for (int i = threadIdx.x; i < 8192; i += 256) {
    unsigned e = (w[2 * i] >> 7) & 0xFF;
    if (e == 0xFF || e < 96) c++;
  }
  atomicAdd(&cnt, c);
  __syncthreads();
  if (threadIdx.x == 0) *flag = (cnt > 512) ? 1 : 0;
}

// ---------------- prep: repack weights + zero state + zero barriers ----------------
__global__ void prep_kernel(const void* Wjx1, const void* Wjh1, const void* Wkx1, const void* Wkh1,
                            const void* Wjx2, const void* Wjh2, const void* Wkx2, const void* Wkh2,
                            const void* Wwin, const void* Wlin,
                            const void* bjx1, const void* bjh1, const void* bkx1, const void* bkh1,
                            const void* bjx2, const void* bjh2, const void* bkx2, const void* bkh2,
                            bf16* W, float* bias,
                            bf16* h1, bf16* h2, bf16* h3, int* bar,
                            const int* flag) {
  const int isF32 = *flag;
  const int r = blockIdx.y;
  const int e = blockIdx.x * 256 + threadIdx.x;
  if (r == 16) {
    if (e < 512) {
      bias[e]        = ldIn(bjx1, e, isF32) + ldIn(bjh1, e, isF32);
      bias[512 + e]  = ldIn(bkx1, e, isF32) + ldIn(bkh1, e, isF32);
      bias[1024 + e] = ldIn(bjx2, e, isF32) + ldIn(bjh2, e, isF32);
      bias[1536 + e] = ldIn(bkx2, e, isF32) + ldIn(bkh2, e, isF32);
    }
    return;
  }
  if (r == 17) {
    if (e < HBUF) {
      h1[HBUF + e] = (bf16)0.f;
      h2[HBUF + e] = (bf16)0.f;
      h3[HBUF + e] = (bf16)0.f;
    }
    if (e < 1024) bar[e] = 0;
    return;
  }
  const int   row0s[16]  = {0,3,0, 0,3,0, 0,515,3,0, 0,515,3,0, 0,0};
  const int   klens[16]  = {3,80,512, 3,80,512, 3,80,512,512, 3,80,512,512, 512,512};
  const int   kpads[16]  = {32,96,512, 32,96,512, 32,96,512,512, 32,96,512,512, 512,512};
  const int   cpads[16]  = {512,512,512, 512,512,512, 512,512,512,512, 512,512,512,512, 32,128};
  const int   nsrcs[16]  = {512,512,512, 512,512,512, 512,512,512,512, 512,512,512,512, 30,121};
  const long  offs[16]   = {W1X_J,W1W_J,W1H_J, W1X_K,W1W_K,W1H_K,
                            W2X_J,W2W_J,W2A_J,W2H_J, W2X_K,W2W_K,W2A_K,W2H_K, WWIN,WLIN};
  const void* srcs[16]   = {Wjx1,Wjx1,Wjh1, Wkx1,Wkx1,Wkh1,
                            Wjx2,Wjx2,Wjx2,Wjh2, Wkx2,Wkx2,Wkx2,Wkh2, Wwin,Wlin};
  const int Kpad = kpads[r], cp = cpads[r];
  const long tot = (long)Kpad * cp;
  if (e >= tot) return;
  const int j    = e & 7;
  const int lane = (e >> 3) & 63;
  const int rest = e >> 9;
  const int kbs  = Kpad >> 5;
  const int kb   = rest % kbs;
  const int slab = rest / kbs;
  const int col  = slab * 16 + (lane & 15);
  const int k    = kb * 32 + ((lane >> 4) << 3) + j;
  const int Klen = klens[r], row0 = row0s[r], N = nsrcs[r];
  bf16 v = (bf16)0.f;
  if (k < Klen && col < N) v = (bf16)ldIn(srcs[r], (long)(row0 + k) * N + col, isF32);
  W[offs[r] + e] = v;
}

// ---------------- shared MFMA helper ----------------
__device__ __forceinline__ void accum_term(f32x4& acc, int& cnt, int kh,
    const bf16* Arow, int astride, const bf16* B, int kbs,
    int lr, int ko, int lane) {
  for (int kb = 0; kb < kbs; ++kb) {
    if (((cnt++) & 1) != kh) continue;
    bf16x8 a = *(const bf16x8*)(Arow + (size_t)lr * astride + kb * 32 + ko);
    bf16x8 b = *(const bf16x8*)(B + ((size_t)kb * 64 + lane) * 8);
    acc = __builtin_amdgcn_mfma_f32_16x16x32_bf16(a, b, acc, 0, 0, 0);
  }
}

// ================= persistent scan kernel =================
__global__ __launch_bounds__(256) void scan_kernel(KParams p) {
  const int isF32 = *p.flag;
  const int tid  = threadIdx.x;
  const int wid  = tid >> 6;
  const int lane = tid & 63;
  const int wg   = blockIdx.x;       // 256 WGs, 1 per CU
  const int m    = wg & 7;           // 8 m-groups; round-robin maps a group onto one XCD
  const int slab = wg >> 3;          // 32 col-slabs (16 cols each)
  const int m16  = m << 4;
  const int lr   = lane & 15;
  const int ko   = (lane >> 4) << 3;
  const int g    = wid >> 1;         // gate (0=j,1=k)
  const int kh   = wid & 1;          // K-half

  unsigned* hg1w = (unsigned*)p.h1;
  unsigned* hg2w = (unsigned*)p.h2;
  unsigned* hg3w = (unsigned*)p.h3;

  // hot W2-cell weights (A_J | A_K | H_J | H_K), 16 KB each, LDS-resident all 600 steps
  __shared__ alignas(16) bf16 wLds[32768];
  __shared__ alignas(16) bf16 h1L[16 * HSTRIDE];
  __shared__ alignas(16) bf16 h2L[16 * HSTRIDE];
  __shared__ alignas(16) bf16 h3L[16 * HSTRIDE];
  __shared__ alignas(16) bf16 xtL[16][32];
  __shared__ alignas(16) bf16 xt2L[16][32];
  __shared__ alignas(16) bf16 wL[16][96];
  __shared__ float kgL[16][32];
  __shared__ float kapL[16][NK];
  __shared__ float alphaL[16][NK];
  __shared__ float betaL[16][NK];
  __shared__ float wloL[16][16];
  __shared__ float whiL[16][16];
  __shared__ int   winL[16][2];
  __shared__ float phiL[16][NU];
  __shared__ f32x4 accA[4][64];
  __shared__ f32x4 accB[4][64];
  __shared__ bf16  hOutA[16][16];
  __shared__ bf16  hOutB[16][16];

  for (int i = tid; i < 16 * 32; i += 256) { (&xtL[0][0])[i] = (bf16)0.f; (&xt2L[0][0])[i] = (bf16)0.f; }
  for (int i = tid; i < 16 * 96; i += 256) (&wL[0][0])[i] = (bf16)0.f;
  for (int i = tid; i < 16 * NK; i += 256) (&kapL[0][0])[i] = 0.f;

  // one-time: DMA the 4 hot weight mats (this slab's slices) into LDS
  {
    const bf16* wsrc[4] = { p.W + W2A_J + (size_t)slab * (16 * NS),
                            p.W + W2A_K + (size_t)slab * (16 * NS),
                            p.W + W2H_J + (size_t)slab * (16 * NS),
                            p.W + W2H_K + (size_t)slab * (16 * NS) };
#pragma unroll
    for (int mt = 0; mt < 4; ++mt) {
#pragma unroll
      for (int r = 0; r < 4; ++r) {
        const int chunk = (wid << 2) + r;   // 0..15, wave-uniform
        __builtin_amdgcn_global_load_lds(
            (const AS1 void*)(wsrc[mt] + chunk * 512 + lane * 8),
            (AS3 void*)(wLds + mt * 8192 + chunk * 512), 16, 0, 0);
      }
    }
  }
  __syncthreads();

  // ---- runtime XCD-locality detection (per launch; both paths numerically identical) ----
  int* gb = p.bar + m * 64;
  {
    int xcc = __builtin_amdgcn_s_getreg((3 << 11) | (0 << 6) | 20) & 31;  // HW_REG_XCC_ID
    if (tid == 0) {
      __hip_atomic_fetch_or((unsigned*)(gb + 32), 1u << xcc,
                            __ATOMIC_RELAXED, __HIP_MEMORY_SCOPE_AGENT);
      __threadfence();   // one-time: ensure the OR is globally visible before arrive
      if ((__hip_atomic_fetch_add(gb + 16, 1, __ATOMIC_RELAXED, __HIP_MEMORY_SCOPE_AGENT) & 31) == 31)
        __hip_atomic_fetch_add(gb + 24, 1, __ATOMIC_RELAXED, __HIP_MEMORY_SCOPE_AGENT);
      while (__hip_atomic_load(gb + 24, __ATOMIC_RELAXED, __HIP_MEMORY_SCOPE_AGENT) < 1)
        __builtin_amdgcn_s_sleep(1);
    }
    __syncthreads();
  }
  const unsigned msk = __hip_atomic_load((unsigned*)(gb + 32),
                                         __ATOMIC_RELAXED, __HIP_MEMORY_SCOPE_AGENT);
  const bool fast = (msk & (msk - 1)) == 0;   // single-XCD group -> L2-local exchange

  const bf16* wA2 = wLds + (size_t)(2 * 0 + 1) * 0;  // resolved per-wave below
  (void)wA2;

  int bt = 0;
  for (int t = -1; t < NT; ++t) {
    const int par_t = t & 1;        // (-1)&1 == 1
    const int par_p = (t + 1) & 1;

    if (t >= 0) {
      // ======== Stage P: attention(t) + ff2(t) + out-head(t-1) ========
      {
        const bf16* g1 = p.h1 + (size_t)par_t * HBUF + (size_t)m16 * NS;
        const bf16* g2 = p.h2 + (size_t)par_p * HBUF + (size_t)m16 * NS;
        const bf16* g3 = p.h3 + (size_t)par_p * HBUF + (size_t)m16 * NS;
        if (fast) {
          stage_tile_async<AUX_SC0>(g1, h1L, tid);
          stage_tile_async<AUX_SC0>(g2, h2L, tid);
          stage_tile_async<AUX_SC0>(g3, h3L, tid);
        } else {
          stage_tile_async<AUX_SC0S1>(g1, h1L, tid);
          stage_tile_async<AUX_SC0S1>(g2, h2L, tid);
          stage_tile_async<AUX_SC0S1>(g3, h3L, tid);
        }
      }
      if (tid < 48) {
        int row = tid / 3, d = tid - row * 3;
        xtL[row][d] = (bf16)ldIn(p.x, ((long)(m16 + row) * NT + t) * 3 + d, isF32);
      }
      __syncthreads();   // drains the DMA (vmcnt) + xt writes
      {  // kg = h1(t) @ W_win via MFMA
        int n2 = wid & 1, kh2 = wid >> 1;
        f32x4 acc = {0.f, 0.f, 0.f, 0.f};
        const bf16* B = p.W + WWIN + (size_t)n2 * (16 * NS);
        for (int kb = 0; kb < 16; ++kb) {
          if ((kb & 1) != kh2) continue;
          bf16x8 a = *(const bf16x8*)(h1L + (size_t)lr * HSTRIDE + kb * 32 + ko);
          bf16x8 b = *(const bf16x8*)(B + ((size_t)kb * 64 + lane) * 8);
          acc = __builtin_amdgcn_mfma_f32_16x16x32_bf16(a, b, acc, 0, 0, 0);
        }
        accA[wid][lane] = acc;
      }
      __syncthreads();
      if (tid < 128) {  // kg epilogue
        int ls = tid & 63, n2s = tid >> 6;
        int o = n2s * 16 + (ls & 15);
        if (o < 30) {
          int rowb = (ls >> 4) << 2;
          for (int r = 0; r < 4; ++r)
            kgL[rowb + r][o] = accA[n2s][ls][r] + accA[n2s + 2][ls][r] + ldIn(p.b_win, o, isF32);
        }
      }
      __syncthreads();
      {  // attention scalars (kap in LDS across steps; same thread owns same slot)
        int arow = tid >> 4, aj = tid & 15;
        if (aj < NK) {
          float ah = kgL[arow][aj];
          float be = expf(kgL[arow][NK + aj]);
          float dk = expf(kgL[arow][2 * NK + aj]);
          float al = expf(ah);
          float kap = kapL[arow][aj] + dk;
          kapL[arow][aj] = kap;
          alphaL[arow][aj] = al;
          betaL[arow][aj] = be;
          float arg = (ah + 18.42f) / be;
          float lo, hi;
          if (arg > 0.f) { float R = sqrtf(arg); lo = kap - R; hi = kap + R; }
          else           { lo = 1e30f; hi = -1e30f; }
          wloL[arow][aj] = lo; whiL[arow][aj] = hi;
        } else { wloL[arow][aj] = 1e30f; whiL[arow][aj] = -1e30f; }
        __syncthreads();
        if (aj == 0) {
          float lo = 1e30f, hi = -1e30f;
          for (int k2 = 0; k2 < NK; ++k2) { lo = fminf(lo, wloL[arow][k2]); hi = fmaxf(hi, whiL[arow][k2]); }
          int ulo = (lo <= 0.f) ? 0 : ((lo > 95.f) ? 96 : (int)floorf(lo));
          int uhi = (hi >= 95.f) ? 95 : ((hi < 0.f) ? -1 : (int)ceilf(hi));
          winL[arow][0] = ulo; winL[arow][1] = uhi;
        }
        __syncthreads();
        const int ulo = winL[arow][0], uhi = winL[arow][1];
        for (int u = ulo + aj; u <= uhi; u += 16) {
          float s = 0.f, uf = (float)u;
          for (int k2 = 0; k2 < NK; ++k2) {
            float d = kapL[arow][k2] - uf;
            s += alphaL[arow][k2] * __expf(-betaL[arow][k2] * d * d);
          }
          phiL[arow][u] = s;
        }
        __syncthreads();
        if (isF32) {  // w = phi @ c_vec[b], vectorized x4; per-c u-order identical to scalar
          const float* cv = (const float*)p.c_vec + (long)(m16 + arow) * NU * NC;
          for (int ch = aj; ch < 20; ch += 16) {
            float a0 = 0.f, a1 = 0.f, a2 = 0.f, a3 = 0.f;
            for (int u = ulo; u <= uhi; ++u) {
              const float* q = cv + (long)u * NC + (ch << 2);
              float ph = phiL[arow][u];
              a0 += ph * q[0]; a1 += ph * q[1]; a2 += ph * q[2]; a3 += ph * q[3];
            }
            wL[arow][(ch << 2) + 0] = (bf16)a0;
            wL[arow][(ch << 2) + 1] = (bf16)a1;
            wL[arow][(ch << 2) + 2] = (bf16)a2;
            wL[arow][(ch << 2) + 3] = (bf16)a3;
          }
        } else {
          const long cv0 = (long)(m16 + arow) * NU * NC;
          for (int c = aj; c < NC; c += 16) {
            float acc = 0.f;
            for (int u = ulo; u <= uhi; ++u)
              acc += phiL[arow][u] * ldIn(p.c_vec, cv0 + (long)u * NC + c, isF32);
            wL[arow][c] = (bf16)acc;
          }
        }
      }
      __syncthreads();
      {  // ff2 MFMAs: in2 = [xt, h1(t), w], recur h2(t-1); A/H weights from LDS
        f32x4 acc = {0.f, 0.f, 0.f, 0.f};
        int cnt = 0;
        const size_t oX = g ? W2X_K : W2X_J, oW = g ? W2W_K : W2W_J;
        const bf16* wA = wLds + (g ? 8192 : 0);
        const bf16* wH = wLds + (g ? 24576 : 16384);
        accum_term(acc, cnt, kh, &xtL[0][0], 32, p.W + oX + (size_t)slab * NS,        1,  lr, ko, lane);
        accum_term(acc, cnt, kh, h1L, HSTRIDE, wA, 16, lr, ko, lane);
        accum_term(acc, cnt, kh, &wL[0][0], 96, p.W + oW + (size_t)slab * (3 * NS),   3,  lr, ko, lane);
        accum_term(acc, cnt, kh, h2L, HSTRIDE, wH, 16, lr, ko, lane);
        accA[wid][lane] = acc;
      }
      if (slab < 8 && t >= 1) {  // out-head MFMAs for rows (t-1): A = h3(par_p) from LDS
        f32x4 acc = {0.f, 0.f, 0.f, 0.f};
        const bf16* B = p.W + WLIN + (size_t)slab * (16 * NS);
        for (int kb = 0; kb < 16; ++kb) {
          if ((kb & 3) != wid) continue;
          bf16x8 a = *(const bf16x8*)(h3L + (size_t)lr * HSTRIDE + kb * 32 + ko);
          bf16x8 b = *(const bf16x8*)(B + ((size_t)kb * 64 + lane) * 8);
          acc = __builtin_amdgcn_mfma_f32_16x16x32_bf16(a, b, acc, 0, 0, 0);
        }
        accB[wid][lane] = acc;
      }
      __syncthreads();
      {  // ff2 epilogue -> h2(t)
        int ls = tid & 63, r = tid >> 6;
        int s = (slab << 4) + (ls & 15);
        int rowIdx = ((ls >> 4) << 2) + r;
        float jp = accA[0][ls][r] + accA[1][ls][r] + p.bias[1024 + s];
        float kp = accA[2][ls][r] + accA[3][ls][r] + p.bias[1536 + s];
        float ho = (float)h2L[rowIdx * HSTRIDE + s];
        float jj = 1.f / (1.f + __expf(-jp));
        float kk = 1.f / (1.f + __expf(-kp));
        hOutA[rowIdx][ls & 15] = (bf16)(jj * (1.f - ho) + (1.f - kk) * ho);
      }
      if (slab < 8 && t >= 1 && tid < 64) {  // out-head epilogue
        int o = (slab << 4) + (tid & 15);
        if (o < NOUT) {
          float bl = ldIn(p.b_lin, o, isF32);
          int rb = (tid >> 4) << 2;
          for (int r = 0; r < 4; ++r) {
            float v = accB[0][tid][r] + accB[1][tid][r] + accB[2][tid][r] + accB[3][tid][r] + bl;
            long oi = ((long)(m16 + rb + r) * NT + (t - 1)) * NOUT + o;
            if (isF32) ((float*)p.out)[oi] = v; else ((bf16*)p.out)[oi] = (bf16)v;
          }
        }
      }
      __syncthreads();
      if (tid < 128) {  // pack + store h2(t) 16x16 tile
        int row = tid >> 3, c = tid & 7;
        union { unsigned u; unsigned short s[2]; } v;
        union { bf16 b; unsigned short s; } a0, a1;
        a0.b = hOutA[row][2 * c]; a1.b = hOutA[row][2 * c + 1];
        v.s[0] = a0.s; v.s[1] = a1.s;
        storeH(hg2w + (size_t)par_t * (HBUF / 2) + (m16 + row) * 256 + slab * 8 + c, v.u, fast);
      }
      group_barrier(gb, ++bt);
    }

    // ======== Stage Q: ff3(t) + ff1(t+1) ========
    if (t >= 0) {
      const bf16* g2 = p.h2 + (size_t)par_t * HBUF + (size_t)m16 * NS;
      if (fast) stage_tile_async<AUX_SC0>(g2, h2L, tid);
      else      stage_tile_async<AUX_SC0S1>(g2, h2L, tid);
    }
    if (t == -1) {
      const bf16* g1 = p.h1 + (size_t)HBUF + (size_t)m16 * NS;   // parity 1 zeros
      if (fast) stage_tile_async<AUX_SC0>(g1, h1L, tid);
      else      stage_tile_async<AUX_SC0S1>(g1, h1L, tid);
    }
    if (t < NT - 1 && tid < 48) {
      int row = tid / 3, d = tid - row * 3;
      xt2L[row][d] = (bf16)ldIn(p.x, ((long)(m16 + row) * NT + (t + 1)) * 3 + d, isF32);
    }
    __syncthreads();
    f32x4 acc3 = {0.f, 0.f, 0.f, 0.f};
    f32x4 acc1 = {0.f, 0.f, 0.f, 0.f};
    if (t >= 0) {  // ff3: in3 = [xt, h2(t), w], recur h3(t-1)  (reuses rnn2 weights from LDS)
      int cnt = 0;
      const size_t oX = g ? W2X_K : W2X_J, oW = g ? W2W_K : W2W_J;
      const bf16* wA = wLds + (g ? 8192 : 0);
      const bf16* wH = wLds + (g ? 24576 : 16384);
      accum_term(acc3, cnt, kh, &xtL[0][0], 32, p.W + oX + (size_t)slab * NS,        1,  lr, ko, lane);
      accum_term(acc3, cnt, kh, h2L, HSTRIDE, wA, 16, lr, ko, lane);
      accum_term(acc3, cnt, kh, &wL[0][0], 96, p.W + oW + (size_t)slab * (3 * NS),   3,  lr, ko, lane);
      accum_term(acc3, cnt, kh, h3L, HSTRIDE, wH, 16, lr, ko, lane);
    }
    if (t < NT - 1) {  // ff1(t+1): in1 = [xt(t+1), w(t)], recur h1(t)
      int cnt = 0;
      const size_t oX = g ? W1X_K : W1X_J, oW = g ? W1W_K : W1W_J, oH = g ? W1H_K : W1H_J;
      accum_term(acc1, cnt, kh, &xt2L[0][0], 32, p.W + oX + (size_t)slab * NS,       1,  lr, ko, lane);
      accum_term(acc1, cnt, kh, &wL[0][0], 96, p.W + oW + (size_t)slab * (3 * NS),   3,  lr, ko, lane);
      accum_term(acc1, cnt, kh, h1L, HSTRIDE, p.W + oH + (size_t)slab * (16 * NS), 16, lr, ko, lane);
    }
    accA[wid][lane] = acc3;
    accB[wid][lane] = acc1;
    __syncthreads();
    {
      int ls = tid & 63, r = tid >> 6;
      int s = (slab << 4) + (ls & 15);
      int rowIdx = ((ls >> 4) << 2) + r;
      if (t >= 0) {  // h3(t)
        float jp = accA[0][ls][r] + accA[1][ls][r] + p.bias[1024 + s];
        float kp = accA[2][ls][r] + accA[3][ls][r] + p.bias[1536 + s];
        float ho = (float)h3L[rowIdx * HSTRIDE + s];
        float jj = 1.f / (1.f + __expf(-jp));
        float kk = 1.f / (1.f + __expf(-kp));
        hOutA[rowIdx][ls & 15] = (bf16)(jj * (1.f - ho) + (1.f - kk) * ho);
      }
      if (t < NT - 1) {  // h1(t+1)
        float jp = accB[0][ls][r] + accB[1][ls][r] + p.bias[0 + s];
        float kp = accB[2][ls][r] + accB[3][ls][r] + p.bias[512 + s];
        float ho = (float)h1L[rowIdx * HSTRIDE + s];
        float jj = 1.f / (1.f + __expf(-jp));
        float kk = 1.f / (1.f + __expf(-kp));
        hOutB[rowIdx][ls & 15] = (bf16)(jj * (1.f - ho) + (1.f - kk) * ho);
      }
    }
    __syncthreads();
    if (t >= 0 && tid < 128) {       // store h3(t)
      int row = tid >> 3, c = tid & 7;
      union { unsigned u; unsigned short s[2]; } v;
      union { bf16 b; unsigned short s; } a0, a1;
      a0.b = hOutA[row][2 * c]; a1.b = hOutA[row][2 * c + 1];
      v.s[0] = a0.s; v.s[1] = a1.s;
      storeH(hg3w + (size_t)par_t * (HBUF / 2) + (m16 + row) * 256 + slab * 8 + c, v.u, fast);
    }
    if (t < NT - 1 && tid >= 128) {  // store h1(t+1)
      int t2 = tid - 128;
      int row = t2 >> 3, c = t2 & 7;
      union { unsigned u; unsigned short s[2]; } v;
      union { bf16 b; unsigned short s; } a0, a1;
      a0.b = hOutB[row][2 * c]; a1.b = hOutB[row][2 * c + 1];
      v.s[0] = a0.s; v.s[1] = a1.s;
      storeH(hg1w + (size_t)par_p * (HBUF / 2) + (m16 + row) * 256 + slab * 8 + c, v.u, fast);
    }
    group_barrier(gb, ++bt);
  }

  // final out-head row t = 599 (h3(599) is in parity 1)
  if (slab < 8) {
    const bf16* g3 = p.h3 + (size_t)HBUF + (size_t)m16 * NS;
    if (fast) stage_tile_async<AUX_SC0>(g3, h3L, tid);
    else      stage_tile_async<AUX_SC0S1>(g3, h3L, tid);
    __syncthreads();
    f32x4 acc = {0.f, 0.f, 0.f, 0.f};
    const bf16* B = p.W + WLIN + (size_t)slab * (16 * NS);
    for (int kb = 0; kb < 16; ++kb) {
      if ((kb & 3) != wid) continue;
      bf16x8 a = *(const bf16x8*)(h3L + (size_t)lr * HSTRIDE + kb * 32 + ko);
      bf16x8 b = *(const bf16x8*)(B + ((size_t)kb * 64 + lane) * 8);
      acc = __builtin_amdgcn_mfma_f32_16x16x32_bf16(a, b, acc, 0, 0, 0);
    }
    accB[wid][lane] = acc;
    __syncthreads();
    if (tid < 64) {
      int o = (slab << 4) + (tid & 15);
      if (o < NOUT) {
        float bl = ldIn(p.b_lin, o, isF32);
        int rb = (tid >> 4) << 2;
        for (int r = 0; r < 4; ++r) {
          float v = accB[0][tid][r] + accB[1][tid][r] + accB[2][tid][r] + accB[3][tid][r] + bl;
          long oi = ((long)(m16 + rb + r) * NT + (NT - 1)) * NOUT + o;
          if (isF32) ((float*)p.out)[oi] = v; else ((bf16*)p.out)[oi] = (bf16)v;
        }
      }
    }
  }
}

extern "C" void kernel_launch(void* const* d_in, const int* in_sizes, int n_in,
                              void* d_out, int out_size, void* d_ws, size_t ws_size,
                              hipStream_t stream) {
  (void)in_sizes; (void)n_in; (void)out_size; (void)ws_size;

  bf16*  wsW  = (bf16*)d_ws;
  float* bias = (float*)((char*)d_ws + BIAS_BYTE_OFF);
  bf16*  h1   = (bf16*)((char*)d_ws + H_BYTE_OFF);
  bf16*  h2   = h1 + 2 * HBUF;
  bf16*  h3   = h2 + 2 * HBUF;
  int*   flag = (int*)((char*)d_ws + FLAG_BYTE_OFF);
  int*   bar  = (int*)((char*)d_ws + BAR_BYTE_OFF);

  sniff_kernel<<<1, 256, 0, stream>>>((const unsigned short*)d_in[4], flag);

  prep_kernel<<<dim3(1024, 18), 256, 0, stream>>>(
      d_in[2], d_in[4], d_in[6], d_in[8], d_in[10], d_in[12], d_in[14], d_in[16],
      d_in[18], d_in[20],
      d_in[3], d_in[5], d_in[7], d_in[9], d_in[11], d_in[13], d_in[15], d_in[17],
      wsW, bias, h1, h2, h3, bar, flag);

  KParams kp;
  kp.x = d_in[0]; kp.c_vec = d_in[1]; kp.b_win = d_in[19]; kp.b_lin = d_in[21];
  kp.W = wsW; kp.bias = bias;
  kp.h1 = h1; kp.h2 = h2; kp.h3 = h3;
  kp.out = d_out;
  kp.flag = flag;
  kp.bar = bar;

  scan_kernel<<<256, 256, 0, stream>>>(kp);
}